// Round 5
// baseline (762.574 us; speedup 1.0000x reference)
//
#include <hip/hip_runtime.h>

#define B    32
#define N1   1024
#define FIN  128
#define NH   256
#define KP1  512
#define KP2  256
#define NCLS 10
#define MAXD 64
#define E1   1.7182818284590452f   // e^LAMB - 1, LAMB = 1.0

// ---------------- tiled GEMM: out[M,256] = A[M,KD] @ W[KD,256] ----------------
template<int KD, int BM, int TM>
__global__ __launch_bounds__(256, 2)
void gemm_kernel(const float* __restrict__ A, const float* __restrict__ W,
                 float* __restrict__ out) {
    constexpr int KC = 16;
    constexpr int SAP = BM + 4;              // padded stride: bank-conflict-free staging
    __shared__ float sw[KC][256];
    __shared__ float sa[KC][SAP];
    int m0 = blockIdx.x * BM;
    int tid = threadIdx.x;
    int ct = tid & 31, rt = tid >> 5;
    int c0 = ct * 8, r0 = rt * TM;
    float acc[TM][8] = {};
    for (int q0 = 0; q0 < KD; q0 += KC) {
        const float4* W4 = (const float4*)(W + q0 * 256);
        for (int i = tid; i < KC * 64; i += 256) {
            int q = i >> 6, c4 = i & 63;
            *(float4*)&sw[q][c4 * 4] = W4[q * 64 + c4];
        }
        const float4* A4 = (const float4*)A;
        for (int i = tid; i < BM * (KC / 4); i += 256) {
            int r = i / (KC / 4), j = i % (KC / 4);
            float4 v = A4[(size_t)(m0 + r) * (KD / 4) + q0 / 4 + j];
            sa[j * 4 + 0][r] = v.x; sa[j * 4 + 1][r] = v.y;
            sa[j * 4 + 2][r] = v.z; sa[j * 4 + 3][r] = v.w;
        }
        __syncthreads();
        #pragma unroll
        for (int q = 0; q < KC; ++q) {
            float wv[8], av[TM];
            *(float4*)&wv[0] = *(const float4*)&sw[q][c0];
            *(float4*)&wv[4] = *(const float4*)&sw[q][c0 + 4];
            #pragma unroll
            for (int j = 0; j < TM / 4; ++j)
                *(float4*)&av[j * 4] = *(const float4*)&sa[q][r0 + j * 4];
            #pragma unroll
            for (int r = 0; r < TM; ++r)
                #pragma unroll
                for (int c = 0; c < 8; ++c)
                    acc[r][c] += av[r] * wv[c];
        }
        __syncthreads();
    }
    for (int r = 0; r < TM; ++r) {
        *(float4*)&out[(size_t)(m0 + r0 + r) * 256 + c0] = *(float4*)&acc[r][0];
        *(float4*)&out[(size_t)(m0 + r0 + r) * 256 + c0 + 4] = *(float4*)&acc[r][4];
    }
}

// ---------------- CSR build: deterministic (column-ordered) ----------------
__global__ __launch_bounds__(256)
void csr_kernel(const float* __restrict__ adj, int* __restrict__ cnt,
                int* __restrict__ nbr, float* __restrict__ dgi,
                float* __restrict__ dia) {
    int row = blockIdx.x;                    // b*N1 + i
    const float* arow = adj + (size_t)row * N1;
    int t = threadIdx.x;                     // 256 threads, 4 cols each
    float4 v4 = ((const float4*)arow)[t];
    int loc[4];
    int c = 0;
    if (v4.x > 0.5f) loc[c++] = t * 4 + 0;
    if (v4.y > 0.5f) loc[c++] = t * 4 + 1;
    if (v4.z > 0.5f) loc[c++] = t * 4 + 2;
    if (v4.w > 0.5f) loc[c++] = t * 4 + 3;
    __shared__ int ps[256];
    ps[t] = c;
    __syncthreads();
    for (int s = 1; s < 256; s <<= 1) {
        int v = (t >= s) ? ps[t - s] : 0;
        __syncthreads();
        ps[t] += v;
        __syncthreads();
    }
    int total = ps[255];
    int off = ps[t] - c;                     // exclusive prefix
    for (int u = 0; u < c; ++u) {
        int p = off + u;
        if (p < MAXD) nbr[(size_t)row * MAXD + p] = loc[u];
    }
    if (t == 0) {
        cnt[row] = min(total, MAXD);
        dgi[row] = rsqrtf((float)total + 1.0f);            // deg of A=adj+I
        dia[row] = total > 0 ? 1.0f / (float)total : 0.0f; // deg of adj
    }
}

// ---------------- stage-1 GCN aggregate: col-slice LDS gather ----------------
__global__ __launch_bounds__(256, 2)
void gcn1_cs_kernel(const float* __restrict__ t1, const int* __restrict__ cnt,
                    const int* __restrict__ nbr, const float* __restrict__ dgi,
                    const float* __restrict__ b1, float* __restrict__ h1) {
    __shared__ float slab[N1][16];           // 64 KB: all rows x 16-col slice
    int b = blockIdx.x >> 4;
    int c0 = (blockIdx.x & 15) * 16;
    int tid = threadIdx.x;
    const float* tb = t1 + (size_t)b * N1 * NH + c0;
    {
        int r = tid >> 2, c4 = (tid & 3) * 4;
        for (int r0 = 0; r0 < N1; r0 += 64)
            *(float4*)&slab[r0 + r][c4] = *(const float4*)&tb[(size_t)(r0 + r) * NH + c4];
    }
    __syncthreads();
    int c = tid & 15, rg = tid >> 4;         // 16 cols x 16 row-groups
    float bf = b1[c0 + c];
    const float* dg = dgi + (b << 10);
    for (int r = rg; r < N1; r += 16) {
        int row = (b << 10) + r;
        int n = cnt[row];
        const int* nb = nbr + (size_t)row * MAXD;
        float a0 = 0.f, a1 = 0.f, a2 = 0.f, a3 = 0.f;
        int e = 0;
        for (; e + 4 <= n; e += 4) {
            int j0 = nb[e], j1 = nb[e + 1], j2 = nb[e + 2], j3 = nb[e + 3];
            a0 += dg[j0] * slab[j0][c]; a1 += dg[j1] * slab[j1][c];
            a2 += dg[j2] * slab[j2][c]; a3 += dg[j3] * slab[j3][c];
        }
        for (; e < n; ++e) { int j = nb[e]; a0 += dg[j] * slab[j][c]; }
        float di = dg[r];
        float v = di * ((a0 + a1) + (a2 + a3) + di * slab[r][c]) + bf;
        h1[(size_t)row * NH + c0 + c] = fmaxf(v, 0.f);
    }
}

// ---------------- stage-1 info score: col-slice, writes per-slice partials ----------------
__global__ __launch_bounds__(256, 2)
void info1_cs_kernel(const float* __restrict__ h1, const int* __restrict__ cnt,
                     const int* __restrict__ nbr, const float* __restrict__ dia,
                     float* __restrict__ part) {
    __shared__ float slab[N1][16];
    int b = blockIdx.x >> 4, sl = blockIdx.x & 15;
    int c0 = sl * 16;
    int tid = threadIdx.x;
    const float* hb = h1 + (size_t)b * N1 * NH + c0;
    {
        int r = tid >> 2, c4 = (tid & 3) * 4;
        for (int r0 = 0; r0 < N1; r0 += 64)
            *(float4*)&slab[r0 + r][c4] = *(const float4*)&hb[(size_t)(r0 + r) * NH + c4];
    }
    __syncthreads();
    int c = tid & 15, rg = tid >> 4;
    for (int r = rg; r < N1; r += 16) {
        int row = (b << 10) + r;
        int n = cnt[row];
        const int* nb = nbr + (size_t)row * MAXD;
        float a0 = 0.f, a1 = 0.f, a2 = 0.f, a3 = 0.f;
        int e = 0;
        for (; e + 4 <= n; e += 4) {
            a0 += slab[nb[e + 0]][c]; a1 += slab[nb[e + 1]][c];
            a2 += slab[nb[e + 2]][c]; a3 += slab[nb[e + 3]][c];
        }
        for (; e < n; ++e) a0 += slab[nb[e]][c];
        float val = fabsf(slab[r][c] - dia[row] * ((a0 + a1) + (a2 + a3)));
        val += __shfl_xor(val, 1); val += __shfl_xor(val, 2);
        val += __shfl_xor(val, 4); val += __shfl_xor(val, 8);
        if (c == 0) part[(size_t)sl * (B * N1) + row] = val;
    }
}

// ---------------- top-k via bitonic sort (desc, tie: lower index first) ----------------
// loads score = sum of PARTS slice-partials (fixed order -> deterministic)
template<int NS, int KS, int NT, bool POS, int PARTS>
__global__ __launch_bounds__(512)
void topk_kernel(const float* __restrict__ part, int* __restrict__ idxo,
                 int* __restrict__ pos) {
    int b = blockIdx.x;
    __shared__ float s[NS];
    __shared__ int id[NS];
    for (int i = threadIdx.x; i < NS; i += NT) {
        float v = 0.f;
        #pragma unroll
        for (int p = 0; p < PARTS; ++p) v += part[(size_t)p * (B * NS) + b * NS + i];
        s[i] = v; id[i] = i;
    }
    __syncthreads();
    for (int ksz = 2; ksz <= NS; ksz <<= 1) {
        for (int j = ksz >> 1; j > 0; j >>= 1) {
            for (int i = threadIdx.x; i < NS; i += NT) {
                int l = i ^ j;
                if (l > i) {
                    float si = s[i], sl = s[l];
                    int ii = id[i], il = id[l];
                    bool iBeforeL = (si > sl) || (si == sl && ii < il);
                    bool dirDesc = ((i & ksz) == 0);
                    if (dirDesc ? !iBeforeL : iBeforeL) {
                        s[i] = sl; s[l] = si; id[i] = il; id[l] = ii;
                    }
                }
            }
            __syncthreads();
        }
    }
    for (int t = threadIdx.x; t < KS; t += NT) idxo[b * KS + t] = id[t];
    if (POS)
        for (int t = threadIdx.x; t < NS; t += NT)
            pos[b * NS + id[t]] = (t < KS) ? t : -1;
}

// ---------------- gather pooled rows + attention dots ----------------
__global__ __launch_bounds__(256)
void gather_att_kernel(const float* __restrict__ h, const int* __restrict__ idx,
                       const float* __restrict__ att, float* __restrict__ hk,
                       float* __restrict__ lv, float* __restrict__ rv,
                       int K, int Nsrc) {
    int g = blockIdx.x;              // b*K + p
    int b = g / K;
    int f = threadIdx.x;
    int src = idx[g];
    float v = h[((size_t)b * Nsrc + src) * NH + f];
    hk[(size_t)g * NH + f] = v;
    __shared__ float r1[256], r2[256];
    r1[f] = v * att[f];
    r2[f] = v * att[NH + f];
    __syncthreads();
    for (int s = 128; s > 0; s >>= 1) {
        if (f < s) { r1[f] += r1[f + s]; r2[f] += r2[f + s]; }
        __syncthreads();
    }
    if (f == 0) { lv[g] = r1[0]; rv[g] = r2[0]; }
}

// ---------------- v = exp(r - rowmax), V = sum v (per batch) ----------------
__global__ __launch_bounds__(512)
void vexp_kernel(const float* __restrict__ rv, float* __restrict__ v1,
                 float* __restrict__ V1) {
    int b = blockIdx.x;
    int t = threadIdx.x;             // 512
    __shared__ float red[512];
    float r = rv[b * KP1 + t];
    red[t] = r;
    __syncthreads();
    for (int s = 256; s > 0; s >>= 1) {
        if (t < s) red[t] = fmaxf(red[t], red[t + s]);
        __syncthreads();
    }
    float mx = red[0];
    __syncthreads();
    float v = expf(r - mx);
    v1[b * KP1 + t] = v;
    red[t] = v;
    __syncthreads();
    for (int s = 256; s > 0; s >>= 1) {
        if (t < s) red[t] += red[t + s];
        __syncthreads();
    }
    if (t == 0) V1[b] = red[0];
}

// ---------------- induced-subgraph CSR on idx1 + Z1 = V + E1*sum_nbr(v) ----------------
__global__ __launch_bounds__(64)
void knbr_kernel(const int* __restrict__ idx1, const int* __restrict__ cnt,
                 const int* __restrict__ nbr, const int* __restrict__ pos1,
                 const float* __restrict__ v1, const float* __restrict__ V1,
                 int* __restrict__ knbr, int* __restrict__ kcnt,
                 float* __restrict__ Z1) {
    int g = blockIdx.x;              // b*KP1 + p
    int b = g / KP1;
    int lane = threadIdx.x;          // 64 = one wave
    int ip = idx1[g];
    int n = cnt[b * N1 + ip];
    int q = -1;
    if (lane < n) {
        int j = nbr[(size_t)(b * N1 + ip) * MAXD + lane];
        q = pos1[b * N1 + j];
    }
    bool kept = q >= 0;
    unsigned long long mask = __ballot(kept);
    int off = __popcll(mask & ((1ull << lane) - 1ull));
    if (kept) knbr[(size_t)g * MAXD + off] = q;
    float s = kept ? v1[b * KP1 + q] : 0.f;
    for (int o = 32; o > 0; o >>= 1) s += __shfl_down(s, o);
    if (lane == 0) { kcnt[g] = __popcll(mask); Z1[g] = V1[b] + E1 * s; }
}

// ---------------- stage-2 GCN: col-slice LDS gather + fused wsum ----------------
__global__ __launch_bounds__(256, 2)
void gcn2_cs_kernel(const float* __restrict__ t2, const float* __restrict__ v1,
                    const float* __restrict__ Z1, const int* __restrict__ knbr,
                    const int* __restrict__ kcnt, const float* __restrict__ b2,
                    float* __restrict__ h2) {
    __shared__ float slab[KP1][16];          // 32 KB
    __shared__ float sv[KP1];
    __shared__ float sz[KP1];
    __shared__ float wpart[16][16];
    int b = blockIdx.x >> 4;
    int c0 = (blockIdx.x & 15) * 16;
    int tid = threadIdx.x;
    const float* tb = t2 + (size_t)b * KP1 * NH + c0;
    {
        int r = tid >> 2, c4 = (tid & 3) * 4;
        for (int r0 = 0; r0 < KP1; r0 += 64)
            *(float4*)&slab[r0 + r][c4] = *(const float4*)&tb[(size_t)(r0 + r) * NH + c4];
    }
    for (int i = tid; i < KP1; i += 256) { sv[i] = v1[b * KP1 + i]; sz[i] = Z1[b * KP1 + i]; }
    __syncthreads();
    int c = tid & 15, rg = tid >> 4;
    float ws = 0.f;
    for (int q = rg; q < KP1; q += 16) ws += sv[q] * slab[q][c];
    wpart[rg][c] = ws;
    __syncthreads();
    float w = 0.f;
    #pragma unroll
    for (int k = 0; k < 16; ++k) w += wpart[k][c];
    float bf = b2[c0 + c];
    for (int r = rg; r < KP1; r += 16) {
        int g = (b << 9) + r;
        int n = kcnt[g];
        const int* nb = knbr + (size_t)g * MAXD;
        float a0 = 0.f, a1 = 0.f, a2 = 0.f, a3 = 0.f;
        int e = 0;
        for (; e + 4 <= n; e += 4) {
            int j0 = nb[e], j1 = nb[e + 1], j2 = nb[e + 2], j3 = nb[e + 3];
            a0 += sv[j0] * slab[j0][c]; a1 += sv[j1] * slab[j1][c];
            a2 += sv[j2] * slab[j2][c]; a3 += sv[j3] * slab[j3][c];
        }
        for (; e < n; ++e) { int j = nb[e]; a0 += sv[j] * slab[j][c]; }
        float agg = (w + E1 * ((a0 + a1) + (a2 + a3))) / sz[r];
        h2[(size_t)g * NH + c0 + c] = fmaxf(0.5f * (agg + slab[r][c]) + bf, 0.f);
    }
}

// ---------------- stage-2 info score: col-slice + fused wsum, partial out ----------------
__global__ __launch_bounds__(256, 2)
void info2_cs_kernel(const float* __restrict__ h2, const float* __restrict__ v1,
                     const float* __restrict__ Z1, const int* __restrict__ knbr,
                     const int* __restrict__ kcnt, float* __restrict__ part) {
    __shared__ float slab[KP1][16];
    __shared__ float sv[KP1];
    __shared__ float sz[KP1];
    __shared__ float wpart[16][16];
    int b = blockIdx.x >> 4, sl = blockIdx.x & 15;
    int c0 = sl * 16;
    int tid = threadIdx.x;
    const float* hb = h2 + (size_t)b * KP1 * NH + c0;
    {
        int r = tid >> 2, c4 = (tid & 3) * 4;
        for (int r0 = 0; r0 < KP1; r0 += 64)
            *(float4*)&slab[r0 + r][c4] = *(const float4*)&hb[(size_t)(r0 + r) * NH + c4];
    }
    for (int i = tid; i < KP1; i += 256) { sv[i] = v1[b * KP1 + i]; sz[i] = Z1[b * KP1 + i]; }
    __syncthreads();
    int c = tid & 15, rg = tid >> 4;
    float ws = 0.f;
    for (int q = rg; q < KP1; q += 16) ws += sv[q] * slab[q][c];
    wpart[rg][c] = ws;
    __syncthreads();
    float w = 0.f;
    #pragma unroll
    for (int k = 0; k < 16; ++k) w += wpart[k][c];
    for (int r = rg; r < KP1; r += 16) {
        int g = (b << 9) + r;
        int n = kcnt[g];
        const int* nb = knbr + (size_t)g * MAXD;
        float a0 = 0.f, a1 = 0.f, a2 = 0.f, a3 = 0.f;
        int e = 0;
        for (; e + 4 <= n; e += 4) {
            int j0 = nb[e], j1 = nb[e + 1], j2 = nb[e + 2], j3 = nb[e + 3];
            a0 += sv[j0] * slab[j0][c]; a1 += sv[j1] * slab[j1][c];
            a2 += sv[j2] * slab[j2][c]; a3 += sv[j3] * slab[j3][c];
        }
        for (; e < n; ++e) { int j = nb[e]; a0 += sv[j] * slab[j][c]; }
        float agg = (w + E1 * ((a0 + a1) + (a2 + a3))) / sz[r];
        float val = fabsf(slab[r][c] - agg);
        val += __shfl_xor(val, 1); val += __shfl_xor(val, 2);
        val += __shfl_xor(val, 4); val += __shfl_xor(val, 8);
        if (c == 0) part[(size_t)sl * (B * KP1) + g] = val;
    }
}

// ---------------- materialize a2 = softmax(r2_q + a1k[p,q]) ----------------
__global__ __launch_bounds__(256)
void a2_kernel(const int* __restrict__ idx2, const float* __restrict__ rv,
               const float* __restrict__ v1, const float* __restrict__ Z1,
               const int* __restrict__ knbr, const int* __restrict__ kcnt,
               float* __restrict__ a2) {
    int g = blockIdx.x;              // b*KP2 + p
    int b = g / KP2;
    int q = threadIdx.x;             // 256
    int p2 = idx2[g];                // position in [0,KP1)
    int gp = b * KP1 + p2;
    __shared__ unsigned char flag[KP1];
    flag[q] = 0; flag[q + 256] = 0;
    __syncthreads();
    int n = kcnt[gp];
    if (q < n) flag[knbr[(size_t)gp * MAXD + q]] = 1;
    __syncthreads();
    int q2 = idx2[b * KP2 + q];
    float a1k = v1[b * KP1 + q2] * (flag[q2] ? (1.f + E1) : 1.f) / Z1[gp];
    float z = rv[b * KP2 + q] + a1k;       // l_p cancels in softmax
    __shared__ float red[256];
    red[q] = z;
    __syncthreads();
    for (int s = 128; s > 0; s >>= 1) {
        if (q < s) red[q] = fmaxf(red[q], red[q + s]);
        __syncthreads();
    }
    float mx = red[0];
    __syncthreads();
    float e = expf(z - mx);
    red[q] = e;
    __syncthreads();
    for (int s = 128; s > 0; s >>= 1) {
        if (q < s) red[q] += red[q + s];
        __syncthreads();
    }
    a2[(size_t)g * KP2 + q] = e / red[0];
}

// ---------------- readout (parallel): rout[b,0:256]=relu(max), [256:512]=relu(mean) ----------------
template<int NROWS, bool INIT>
__global__ __launch_bounds__(1024)
void readout_kernel(const float* __restrict__ h, float* __restrict__ rout) {
    int b = blockIdx.x;
    int f = threadIdx.x & 255, c = threadIdx.x >> 8;   // 1024 threads: 4 row-chunks
    const float* hb = h + (size_t)b * NROWS * NH;
    float mx = -1e30f, sm = 0.f;
    for (int p = c; p < NROWS; p += 4) {
        float v = hb[(size_t)p * NH + f];
        mx = fmaxf(mx, v);
        sm += v;
    }
    __shared__ float rm[4][256], rs[4][256];
    rm[c][f] = mx; rs[c][f] = sm;
    __syncthreads();
    if (c == 0) {
        #pragma unroll
        for (int j = 1; j < 4; ++j) { mx = fmaxf(mx, rm[j][f]); sm += rs[j][f]; }
        float rmv = fmaxf(mx, 0.f);
        float rav = fmaxf(sm * (1.0f / NROWS), 0.f);
        if (INIT) { rout[b * 512 + f] = rmv;  rout[b * 512 + NH + f] = rav; }
        else      { rout[b * 512 + f] += rmv; rout[b * 512 + NH + f] += rav; }
    }
}

// ---------------- fused stage-3: h3 = relu(0.5*(a2@t3 + t3) + b3) -> readout += ----------------
__global__ __launch_bounds__(256, 2)
void gcn3_fused_kernel(const float* __restrict__ a2, const float* __restrict__ t3,
                       const float* __restrict__ b3, float* __restrict__ rout) {
    constexpr int KC = 16;
    __shared__ float sa[KC][260];            // padded: conflict-free staging
    __shared__ float st[KC][32];
    int b = blockIdx.x >> 3;
    int cb = (blockIdx.x & 7) * 32;
    int tid = threadIdx.x;
    int ct = tid & 7, rt = tid >> 3;
    int c0 = cb + ct * 4, r0 = rt * 8;
    const float* ab = a2 + (size_t)b * KP2 * KP2;
    const float* tb = t3 + (size_t)b * KP2 * NH;
    float acc[8][4] = {};
    for (int q0 = 0; q0 < KP2; q0 += KC) {
        const float4* A4 = (const float4*)ab;
        for (int i = tid; i < 256 * (KC / 4); i += 256) {
            int r = i >> 2, j = i & 3;
            float4 v = A4[(size_t)r * 64 + q0 / 4 + j];
            sa[j * 4 + 0][r] = v.x; sa[j * 4 + 1][r] = v.y;
            sa[j * 4 + 2][r] = v.z; sa[j * 4 + 3][r] = v.w;
        }
        if (tid < KC * 8) {
            int q = tid >> 3, c4 = tid & 7;
            *(float4*)&st[q][c4 * 4] = *(const float4*)&tb[(size_t)(q0 + q) * NH + cb + c4 * 4];
        }
        __syncthreads();
        #pragma unroll
        for (int q = 0; q < KC; ++q) {
            float tv[4], av[8];
            *(float4*)&tv[0] = *(const float4*)&st[q][ct * 4];
            *(float4*)&av[0] = *(const float4*)&sa[q][r0];
            *(float4*)&av[4] = *(const float4*)&sa[q][r0 + 4];
            #pragma unroll
            for (int r = 0; r < 8; ++r)
                #pragma unroll
                for (int c = 0; c < 4; ++c)
                    acc[r][c] += av[r] * tv[c];
        }
        __syncthreads();
    }
    float bv[4];
    *(float4*)&bv[0] = *(const float4*)&b3[c0];
    float mx[4] = {-1e30f, -1e30f, -1e30f, -1e30f}, sm[4] = {};
    for (int r = 0; r < 8; ++r) {
        float4 t4 = *(const float4*)&tb[(size_t)(r0 + r) * NH + c0];
        float tvv[4] = {t4.x, t4.y, t4.z, t4.w};
        #pragma unroll
        for (int c = 0; c < 4; ++c) {
            float h = fmaxf(0.5f * (acc[r][c] + tvv[c]) + bv[c], 0.f);
            mx[c] = fmaxf(mx[c], h);
            sm[c] += h;
        }
    }
    __shared__ float rmx[32][33], rsm[32][33];
    #pragma unroll
    for (int c = 0; c < 4; ++c) { rmx[ct * 4 + c][rt] = mx[c]; rsm[ct * 4 + c][rt] = sm[c]; }
    __syncthreads();
    if (tid < 32) {
        float m = -1e30f, s = 0.f;
        for (int r = 0; r < 32; ++r) { m = fmaxf(m, rmx[tid][r]); s += rsm[tid][r]; }
        rout[b * 512 + cb + tid] += fmaxf(m, 0.f);
        rout[b * 512 + NH + cb + tid] += fmaxf(s * (1.f / KP2), 0.f);
    }
}

// ---------------- final linear (parallel over f-chunks) ----------------
__global__ __launch_bounds__(256)
void final_kernel(const float* __restrict__ rout, const float* __restrict__ Wlin,
                  const float* __restrict__ blin, float* __restrict__ out) {
    int b = blockIdx.x;
    int tid = threadIdx.x;
    int c = tid & 15, fg = tid >> 4;         // 16 f-groups x 16 (10 used) cols
    float acc = 0.f;
    if (c < NCLS) {
        for (int k = 0; k < 32; ++k) {
            int f = fg * 32 + k;
            acc += rout[b * 512 + f] * Wlin[f * NCLS + c];
        }
    }
    __shared__ float red[16][16];
    red[fg][c] = acc;
    __syncthreads();
    if (tid < 16 && c < NCLS) {
        float a = blin[c];
        #pragma unroll
        for (int k = 0; k < 16; ++k) a += red[k][c];
        out[b * NCLS + c] = a;
    }
}

extern "C" void kernel_launch(void* const* d_in, const int* in_sizes, int n_in,
                              void* d_out, int out_size, void* d_ws, size_t ws_size,
                              hipStream_t stream) {
    const float* x    = (const float*)d_in[0];
    const float* adj  = (const float*)d_in[1];
    const float* W1   = (const float*)d_in[2];
    const float* b1   = (const float*)d_in[3];
    const float* W2   = (const float*)d_in[4];
    const float* b2   = (const float*)d_in[5];
    const float* W3   = (const float*)d_in[6];
    const float* b3   = (const float*)d_in[7];
    const float* att1 = (const float*)d_in[8];
    const float* att2 = (const float*)d_in[9];
    const float* Wlin = (const float*)d_in[10];
    const float* blin = (const float*)d_in[11];
    float* out = (float*)d_out;

    float* fws = (float*)d_ws;
    float* t1  = fws;                        // 8,388,608 floats
    float* h1  = t1 + 8388608;               // 8,388,608
    float* hk  = h1 + 8388608;               // 4,194,304
    float* dgi = hk + 4194304;               // 32768
    float* dia = dgi + 32768;                // 32768
    float* parts1 = dia + 32768;             // 16*B*N1 = 524288
    float* parts2 = parts1 + 524288;         // 16*B*KP1 = 262144
    float* lv  = parts2 + 262144;            // 16384
    float* rv  = lv + 16384;                 // 16384
    float* rout = rv + 16384;                // 16384
    float* v1  = rout + 16384;               // 16384
    float* V1  = v1 + 16384;                 // 64 (padded)
    float* Z1  = V1 + 64;                    // 16384
    int* cnt  = (int*)(Z1 + 16384);          // 32768
    int* nbr  = cnt + 32768;                 // 32768*64 = 2,097,152
    int* idx1 = nbr + 32768 * MAXD;          // 16384
    int* idx2 = idx1 + 16384;                // 8192
    int* pos1 = idx2 + 8192;                 // 32768
    // aliases (lifetime-disjoint reuse)
    float* t2   = h1;                        // stage-2 XW   [B*KP1*NH]
    float* h2   = h1 + 4194304;              // stage-2 hidden
    float* h2k  = hk;                        // stage-2 pooled rows
    float* a2   = t1;                        // [B*KP2*KP2] = 2,097,152 (t1 dead after gcn1)
    float* t3   = t1 + 2097152;              // 2,097,152
    int*   knbr = (int*)(t1 + 6291456);      // 16384*64 = 1,048,576 ints
    int*   kcnt = knbr + 16384 * MAXD;       // 16384

    // ---- stage 1 (sparse binary graph) ----
    gemm_kernel<FIN, 64, 8><<<512, 256, 0, stream>>>(x, W1, t1);
    csr_kernel<<<B * N1, 256, 0, stream>>>(adj, cnt, nbr, dgi, dia);
    gcn1_cs_kernel<<<B * 16, 256, 0, stream>>>(t1, cnt, nbr, dgi, b1, h1);
    info1_cs_kernel<<<B * 16, 256, 0, stream>>>(h1, cnt, nbr, dia, parts1);
    topk_kernel<N1, KP1, 512, true, 16><<<B, 512, 0, stream>>>(parts1, idx1, pos1);
    gather_att_kernel<<<B * KP1, 256, 0, stream>>>(h1, idx1, att1, hk, lv, rv, KP1, N1);
    readout_kernel<KP1, true><<<B, 1024, 0, stream>>>(hk, rout);

    // ---- pool-1 factorization: a1[p,q] = v_q*(1+E1*adjk)/Z_p ----
    vexp_kernel<<<B, 512, 0, stream>>>(rv, v1, V1);
    knbr_kernel<<<B * KP1, 64, 0, stream>>>(idx1, cnt, nbr, pos1, v1, V1, knbr, kcnt, Z1);

    // ---- stage 2 (factorized a1, fused wsum) ----
    gemm_kernel<NH, 64, 8><<<256, 256, 0, stream>>>(hk, W2, t2);
    gcn2_cs_kernel<<<B * 16, 256, 0, stream>>>(t2, v1, Z1, knbr, kcnt, b2, h2);
    info2_cs_kernel<<<B * 16, 256, 0, stream>>>(h2, v1, Z1, knbr, kcnt, parts2);
    topk_kernel<KP1, KP2, 512, false, 16><<<B, 512, 0, stream>>>(parts2, idx2, nullptr);
    gather_att_kernel<<<B * KP2, 256, 0, stream>>>(h2, idx2, att2, h2k, lv, rv, KP2, KP1);
    readout_kernel<KP2, false><<<B, 1024, 0, stream>>>(h2k, rout);
    a2_kernel<<<B * KP2, 256, 0, stream>>>(idx2, rv, v1, Z1, knbr, kcnt, a2);

    // ---- stage 3 (fused dense GCN + readout) ----
    gemm_kernel<NH, 32, 4><<<256, 256, 0, stream>>>(h2k, W3, t3);
    gcn3_fused_kernel<<<B * 8, 256, 0, stream>>>(a2, t3, b3, rout);

    // ---- classifier ----
    final_kernel<<<B, 256, 0, stream>>>(rout, Wlin, blin, out);
}

// Round 6
// 462.623 us; speedup vs baseline: 1.6484x; 1.6484x over previous
//
#include <hip/hip_runtime.h>

#define B    32
#define N1   1024
#define FIN  128
#define NH   256
#define KP1  512
#define KP2  256
#define NCLS 10
#define MAXD 64
#define E1   1.7182818284590452f   // e^LAMB - 1, LAMB = 1.0

// ---------------- tiled GEMM: out[M,256] = A[M,KD] @ W[KD,256], BM=32 ----------------
// 256 threads = 32 col-threads (8 cols) x 8 row-threads (4 rows)
template<int KD>
__global__ __launch_bounds__(256, 4)
void gemm_kernel(const float* __restrict__ A, const float* __restrict__ W,
                 float* __restrict__ out) {
    constexpr int KC = 16;
    constexpr int BM = 32, TM = 4;
    __shared__ float sw[KC][256];
    __shared__ float sa[KC][BM + 4];
    int m0 = blockIdx.x * BM;
    int tid = threadIdx.x;
    int ct = tid & 31, rt = tid >> 5;
    int c0 = ct * 8, r0 = rt * TM;
    float acc[TM][8] = {};
    for (int q0 = 0; q0 < KD; q0 += KC) {
        const float4* W4 = (const float4*)(W + q0 * 256);
        for (int i = tid; i < KC * 64; i += 256) {
            int q = i >> 6, c4 = i & 63;
            *(float4*)&sw[q][c4 * 4] = W4[q * 64 + c4];
        }
        const float4* A4 = (const float4*)A;
        for (int i = tid; i < BM * (KC / 4); i += 256) {
            int r = i / (KC / 4), j = i % (KC / 4);
            float4 v = A4[(size_t)(m0 + r) * (KD / 4) + q0 / 4 + j];
            sa[j * 4 + 0][r] = v.x; sa[j * 4 + 1][r] = v.y;
            sa[j * 4 + 2][r] = v.z; sa[j * 4 + 3][r] = v.w;
        }
        __syncthreads();
        #pragma unroll
        for (int q = 0; q < KC; ++q) {
            float wv[8], av[TM];
            *(float4*)&wv[0] = *(const float4*)&sw[q][c0];
            *(float4*)&wv[4] = *(const float4*)&sw[q][c0 + 4];
            *(float4*)&av[0] = *(const float4*)&sa[q][r0];
            #pragma unroll
            for (int r = 0; r < TM; ++r)
                #pragma unroll
                for (int c = 0; c < 8; ++c)
                    acc[r][c] += av[r] * wv[c];
        }
        __syncthreads();
    }
    for (int r = 0; r < TM; ++r) {
        *(float4*)&out[(size_t)(m0 + r0 + r) * 256 + c0] = *(float4*)&acc[r][0];
        *(float4*)&out[(size_t)(m0 + r0 + r) * 256 + c0 + 4] = *(float4*)&acc[r][4];
    }
}

// ---------------- CSR build: deterministic (column-ordered) ----------------
__global__ __launch_bounds__(256)
void csr_kernel(const float* __restrict__ adj, int* __restrict__ cnt,
                int* __restrict__ nbr, float* __restrict__ dgi,
                float* __restrict__ dia) {
    int row = blockIdx.x;                    // b*N1 + i
    const float* arow = adj + (size_t)row * N1;
    int t = threadIdx.x;                     // 256 threads, 4 cols each
    float4 v4 = ((const float4*)arow)[t];
    int loc[4];
    int c = 0;
    if (v4.x > 0.5f) loc[c++] = t * 4 + 0;
    if (v4.y > 0.5f) loc[c++] = t * 4 + 1;
    if (v4.z > 0.5f) loc[c++] = t * 4 + 2;
    if (v4.w > 0.5f) loc[c++] = t * 4 + 3;
    __shared__ int ps[256];
    ps[t] = c;
    __syncthreads();
    for (int s = 1; s < 256; s <<= 1) {
        int v = (t >= s) ? ps[t - s] : 0;
        __syncthreads();
        ps[t] += v;
        __syncthreads();
    }
    int total = ps[255];
    int off = ps[t] - c;                     // exclusive prefix
    for (int u = 0; u < c; ++u) {
        int p = off + u;
        if (p < MAXD) nbr[(size_t)row * MAXD + p] = loc[u];
    }
    if (t == 0) {
        cnt[row] = min(total, MAXD);
        dgi[row] = rsqrtf((float)total + 1.0f);            // deg of A=adj+I
        dia[row] = total > 0 ? 1.0f / (float)total : 0.0f; // deg of adj
    }
}

// ---------------- stage-1 GCN aggregate (sparse, XCD-clustered) ----------------
__global__ __launch_bounds__(256)
void gcn1_kernel(const float* __restrict__ t1, const int* __restrict__ cnt,
                 const int* __restrict__ nbr, const float* __restrict__ dgi,
                 const float* __restrict__ b1, float* __restrict__ h1) {
    int j = blockIdx.x;
    int b = j & 31, i = j >> 5;              // batch b -> XCD b%8 (round-robin dispatch)
    int row = (b << 10) + i;
    int f = threadIdx.x;
    const float* tb = t1 + (size_t)b * N1 * NH;
    int n = cnt[row];
    __shared__ int lst[MAXD];
    __shared__ float sdg[MAXD];
    if (threadIdx.x < n) {
        int jj = nbr[(size_t)row * MAXD + threadIdx.x];
        lst[threadIdx.x] = jj;
        sdg[threadIdx.x] = dgi[(b << 10) + jj];
    }
    __syncthreads();
    float a0 = 0.f, a1 = 0.f, a2 = 0.f, a3 = 0.f;
    int e = 0;
    for (; e + 4 <= n; e += 4) {
        a0 += sdg[e + 0] * tb[(size_t)lst[e + 0] * NH + f];
        a1 += sdg[e + 1] * tb[(size_t)lst[e + 1] * NH + f];
        a2 += sdg[e + 2] * tb[(size_t)lst[e + 2] * NH + f];
        a3 += sdg[e + 3] * tb[(size_t)lst[e + 3] * NH + f];
    }
    for (; e < n; ++e) a0 += sdg[e] * tb[(size_t)lst[e] * NH + f];
    float acc = (a0 + a1) + (a2 + a3);
    float di = dgi[row];
    float v = di * (acc + di * tb[(size_t)i * NH + f]) + b1[f];
    h1[(size_t)row * NH + f] = fmaxf(v, 0.f);
}

// ---------------- stage-1 info score (sparse, XCD-clustered) ----------------
__global__ __launch_bounds__(256)
void info1_kernel(const float* __restrict__ h1, const int* __restrict__ cnt,
                  const int* __restrict__ nbr, const float* __restrict__ dia,
                  float* __restrict__ sc) {
    int j = blockIdx.x;
    int b = j & 31, i = j >> 5;
    int row = (b << 10) + i;
    int f = threadIdx.x;
    const float* hb = h1 + (size_t)b * N1 * NH;
    int n = cnt[row];
    __shared__ int lst[MAXD];
    if (threadIdx.x < n) lst[threadIdx.x] = nbr[(size_t)row * MAXD + threadIdx.x];
    __syncthreads();
    float a0 = 0.f, a1 = 0.f, a2 = 0.f, a3 = 0.f;
    int e = 0;
    for (; e + 4 <= n; e += 4) {
        a0 += hb[(size_t)lst[e + 0] * NH + f];
        a1 += hb[(size_t)lst[e + 1] * NH + f];
        a2 += hb[(size_t)lst[e + 2] * NH + f];
        a3 += hb[(size_t)lst[e + 3] * NH + f];
    }
    for (; e < n; ++e) a0 += hb[(size_t)lst[e] * NH + f];
    float acc = (a0 + a1) + (a2 + a3);
    float val = fabsf(hb[(size_t)i * NH + f] - dia[row] * acc);
    val += __shfl_xor(val, 32); val += __shfl_xor(val, 16);
    val += __shfl_xor(val, 8);  val += __shfl_xor(val, 4);
    val += __shfl_xor(val, 2);  val += __shfl_xor(val, 1);
    __shared__ float ws[4];
    if ((f & 63) == 0) ws[f >> 6] = val;
    __syncthreads();
    if (f == 0) sc[row] = (ws[0] + ws[1]) + (ws[2] + ws[3]);
}

// ---------------- top-k via bitonic sort (desc, tie: lower index first) ----------------
template<int NS, int KS, int NT, bool POS>
__global__ __launch_bounds__(512)
void topk_kernel(const float* __restrict__ sc, int* __restrict__ idxo,
                 int* __restrict__ pos) {
    int b = blockIdx.x;
    __shared__ float s[NS];
    __shared__ int id[NS];
    for (int i = threadIdx.x; i < NS; i += NT) { s[i] = sc[b * NS + i]; id[i] = i; }
    __syncthreads();
    for (int ksz = 2; ksz <= NS; ksz <<= 1) {
        for (int j = ksz >> 1; j > 0; j >>= 1) {
            for (int i = threadIdx.x; i < NS; i += NT) {
                int l = i ^ j;
                if (l > i) {
                    float si = s[i], sl = s[l];
                    int ii = id[i], il = id[l];
                    bool iBeforeL = (si > sl) || (si == sl && ii < il);
                    bool dirDesc = ((i & ksz) == 0);
                    if (dirDesc ? !iBeforeL : iBeforeL) {
                        s[i] = sl; s[l] = si; id[i] = il; id[l] = ii;
                    }
                }
            }
            __syncthreads();
        }
    }
    for (int t = threadIdx.x; t < KS; t += NT) idxo[b * KS + t] = id[t];
    if (POS)
        for (int t = threadIdx.x; t < NS; t += NT)
            pos[b * NS + id[t]] = (t < KS) ? t : -1;
}

// ---------------- gather pooled rows + attention dots (XCD-clustered) ----------------
__global__ __launch_bounds__(256)
void gather_att_kernel(const float* __restrict__ h, const int* __restrict__ idx,
                       const float* __restrict__ att, float* __restrict__ hk,
                       float* __restrict__ lv, float* __restrict__ rv,
                       int K, int Nsrc) {
    int j = blockIdx.x;
    int b = j & 31, p = j >> 5;
    int g = b * K + p;
    int f = threadIdx.x;
    int src = idx[g];
    float v = h[((size_t)b * Nsrc + src) * NH + f];
    hk[(size_t)g * NH + f] = v;
    float r1 = v * att[f];
    float r2 = v * att[NH + f];
    r1 += __shfl_xor(r1, 32); r2 += __shfl_xor(r2, 32);
    r1 += __shfl_xor(r1, 16); r2 += __shfl_xor(r2, 16);
    r1 += __shfl_xor(r1, 8);  r2 += __shfl_xor(r2, 8);
    r1 += __shfl_xor(r1, 4);  r2 += __shfl_xor(r2, 4);
    r1 += __shfl_xor(r1, 2);  r2 += __shfl_xor(r2, 2);
    r1 += __shfl_xor(r1, 1);  r2 += __shfl_xor(r2, 1);
    __shared__ float s1[4], s2[4];
    if ((f & 63) == 0) { s1[f >> 6] = r1; s2[f >> 6] = r2; }
    __syncthreads();
    if (f == 0) {
        lv[g] = (s1[0] + s1[1]) + (s1[2] + s1[3]);
        rv[g] = (s2[0] + s2[1]) + (s2[2] + s2[3]);
    }
}

// ---------------- v = exp(r - rowmax), V = sum v (per batch) ----------------
__global__ __launch_bounds__(512)
void vexp_kernel(const float* __restrict__ rv, float* __restrict__ v1,
                 float* __restrict__ V1) {
    int b = blockIdx.x;
    int t = threadIdx.x;             // 512
    __shared__ float red[512];
    float r = rv[b * KP1 + t];
    red[t] = r;
    __syncthreads();
    for (int s = 256; s > 0; s >>= 1) {
        if (t < s) red[t] = fmaxf(red[t], red[t + s]);
        __syncthreads();
    }
    float mx = red[0];
    __syncthreads();
    float v = expf(r - mx);
    v1[b * KP1 + t] = v;
    red[t] = v;
    __syncthreads();
    for (int s = 256; s > 0; s >>= 1) {
        if (t < s) red[t] += red[t + s];
        __syncthreads();
    }
    if (t == 0) V1[b] = red[0];
}

// ---------------- induced-subgraph CSR on idx1 + Z1 (XCD-clustered) ----------------
__global__ __launch_bounds__(64)
void knbr_kernel(const int* __restrict__ idx1, const int* __restrict__ cnt,
                 const int* __restrict__ nbr, const int* __restrict__ pos1,
                 const float* __restrict__ v1, const float* __restrict__ V1,
                 int* __restrict__ knbr, int* __restrict__ kcnt,
                 float* __restrict__ Z1) {
    int j = blockIdx.x;
    int b = j & 31, p = j >> 5;
    int g = b * KP1 + p;
    int lane = threadIdx.x;          // 64 = one wave
    int ip = idx1[g];
    int n = cnt[b * N1 + ip];
    int q = -1;
    if (lane < n) {
        int jj = nbr[(size_t)(b * N1 + ip) * MAXD + lane];
        q = pos1[b * N1 + jj];
    }
    bool kept = q >= 0;
    unsigned long long mask = __ballot(kept);
    int off = __popcll(mask & ((1ull << lane) - 1ull));
    if (kept) knbr[(size_t)g * MAXD + off] = q;
    float s = kept ? v1[b * KP1 + q] : 0.f;
    for (int o = 32; o > 0; o >>= 1) s += __shfl_down(s, o);
    if (lane == 0) { kcnt[g] = __popcll(mask); Z1[g] = V1[b] + E1 * s; }
}

// ---------------- per-batch weighted column sum (partials over 8 chunks) ----------------
__global__ __launch_bounds__(256)
void wsum_kernel(const float* __restrict__ X, const float* __restrict__ v1,
                 float* __restrict__ wp) {
    int blk = blockIdx.x;            // b*8 + c
    int b = blk >> 3, c = blk & 7;
    int f = threadIdx.x;
    float a0 = 0.f, a1 = 0.f, a2 = 0.f, a3 = 0.f;
    for (int q = c * 64; q < c * 64 + 64; q += 4) {
        a0 += v1[b * KP1 + q + 0] * X[(size_t)(b * KP1 + q + 0) * NH + f];
        a1 += v1[b * KP1 + q + 1] * X[(size_t)(b * KP1 + q + 1) * NH + f];
        a2 += v1[b * KP1 + q + 2] * X[(size_t)(b * KP1 + q + 2) * NH + f];
        a3 += v1[b * KP1 + q + 3] * X[(size_t)(b * KP1 + q + 3) * NH + f];
    }
    wp[(size_t)blk * NH + f] = (a0 + a1) + (a2 + a3);
}

// ---------------- stage-2 GCN via factorized a1 (XCD-clustered) ----------------
__global__ __launch_bounds__(256)
void gcn2_kernel(const float* __restrict__ t2, const float* __restrict__ wp,
                 const float* __restrict__ v1, const float* __restrict__ Z1,
                 const int* __restrict__ knbr, const int* __restrict__ kcnt,
                 const float* __restrict__ b2, float* __restrict__ h2) {
    int j = blockIdx.x;
    int b = j & 31, p = j >> 5;
    int g = b * KP1 + p;
    int f = threadIdx.x;
    __shared__ int lst[MAXD];
    __shared__ float wv[MAXD];
    int n = kcnt[g];
    if (threadIdx.x < n) {
        int q = knbr[(size_t)g * MAXD + threadIdx.x];
        lst[threadIdx.x] = q;
        wv[threadIdx.x] = v1[b * KP1 + q];
    }
    __syncthreads();
    float a0 = 0.f, a1 = 0.f, a2 = 0.f, a3 = 0.f;
    int e = 0;
    for (; e + 4 <= n; e += 4) {
        a0 += wv[e + 0] * t2[(size_t)(b * KP1 + lst[e + 0]) * NH + f];
        a1 += wv[e + 1] * t2[(size_t)(b * KP1 + lst[e + 1]) * NH + f];
        a2 += wv[e + 2] * t2[(size_t)(b * KP1 + lst[e + 2]) * NH + f];
        a3 += wv[e + 3] * t2[(size_t)(b * KP1 + lst[e + 3]) * NH + f];
    }
    for (; e < n; ++e) a0 += wv[e] * t2[(size_t)(b * KP1 + lst[e]) * NH + f];
    float acc = (a0 + a1) + (a2 + a3);
    float w = 0.f;
    #pragma unroll
    for (int c = 0; c < 8; ++c) w += wp[(size_t)(b * 8 + c) * NH + f];
    float agg = (w + E1 * acc) / Z1[g];
    float tv = t2[(size_t)g * NH + f];
    h2[(size_t)g * NH + f] = fmaxf(0.5f * (agg + tv) + b2[f], 0.f);
}

// ---------------- stage-2 info score via factorized a1 (XCD-clustered) ----------------
__global__ __launch_bounds__(256)
void info2_kernel(const float* __restrict__ h2, const float* __restrict__ wp,
                  const float* __restrict__ v1, const float* __restrict__ Z1,
                  const int* __restrict__ knbr, const int* __restrict__ kcnt,
                  float* __restrict__ sc) {
    int j = blockIdx.x;
    int b = j & 31, p = j >> 5;
    int g = b * KP1 + p;
    int f = threadIdx.x;
    __shared__ int lst[MAXD];
    __shared__ float wv[MAXD];
    int n = kcnt[g];
    if (threadIdx.x < n) {
        int q = knbr[(size_t)g * MAXD + threadIdx.x];
        lst[threadIdx.x] = q;
        wv[threadIdx.x] = v1[b * KP1 + q];
    }
    __syncthreads();
    float a0 = 0.f, a1 = 0.f, a2 = 0.f, a3 = 0.f;
    int e = 0;
    for (; e + 4 <= n; e += 4) {
        a0 += wv[e + 0] * h2[(size_t)(b * KP1 + lst[e + 0]) * NH + f];
        a1 += wv[e + 1] * h2[(size_t)(b * KP1 + lst[e + 1]) * NH + f];
        a2 += wv[e + 2] * h2[(size_t)(b * KP1 + lst[e + 2]) * NH + f];
        a3 += wv[e + 3] * h2[(size_t)(b * KP1 + lst[e + 3]) * NH + f];
    }
    for (; e < n; ++e) a0 += wv[e] * h2[(size_t)(b * KP1 + lst[e]) * NH + f];
    float acc = (a0 + a1) + (a2 + a3);
    float w = 0.f;
    #pragma unroll
    for (int c = 0; c < 8; ++c) w += wp[(size_t)(b * 8 + c) * NH + f];
    float agg = (w + E1 * acc) / Z1[g];
    float val = fabsf(h2[(size_t)g * NH + f] - agg);
    val += __shfl_xor(val, 32); val += __shfl_xor(val, 16);
    val += __shfl_xor(val, 8);  val += __shfl_xor(val, 4);
    val += __shfl_xor(val, 2);  val += __shfl_xor(val, 1);
    __shared__ float ws[4];
    if ((f & 63) == 0) ws[f >> 6] = val;
    __syncthreads();
    if (f == 0) sc[g] = (ws[0] + ws[1]) + (ws[2] + ws[3]);
}

// ---------------- materialize a2 = softmax(r2_q + a1k[p,q]) (XCD-clustered) ----------------
__global__ __launch_bounds__(256)
void a2_kernel(const int* __restrict__ idx2, const float* __restrict__ rv,
               const float* __restrict__ v1, const float* __restrict__ Z1,
               const int* __restrict__ knbr, const int* __restrict__ kcnt,
               float* __restrict__ a2) {
    int j = blockIdx.x;
    int b = j & 31, p = j >> 5;
    int g = b * KP2 + p;
    int q = threadIdx.x;             // 256
    int p2 = idx2[g];                // position in [0,KP1)
    int gp = b * KP1 + p2;
    __shared__ unsigned char flag[KP1];
    flag[q] = 0; flag[q + 256] = 0;
    __syncthreads();
    int n = kcnt[gp];
    if (q < n) flag[knbr[(size_t)gp * MAXD + q]] = 1;
    __syncthreads();
    int q2 = idx2[b * KP2 + q];
    float a1k = v1[b * KP1 + q2] * (flag[q2] ? (1.f + E1) : 1.f) / Z1[gp];
    float z = rv[b * KP2 + q] + a1k;       // l_p cancels in softmax
    __shared__ float red[256];
    red[q] = z;
    __syncthreads();
    for (int s = 128; s > 0; s >>= 1) {
        if (q < s) red[q] = fmaxf(red[q], red[q + s]);
        __syncthreads();
    }
    float mx = red[0];
    __syncthreads();
    float e = expf(z - mx);
    red[q] = e;
    __syncthreads();
    for (int s = 128; s > 0; s >>= 1) {
        if (q < s) red[q] += red[q + s];
        __syncthreads();
    }
    a2[(size_t)g * KP2 + q] = e / red[0];
}

// ---------------- readout (parallel): rout[b,0:256]=relu(max), [256:512]=relu(mean) ----------------
template<int NROWS, bool INIT>
__global__ __launch_bounds__(1024)
void readout_kernel(const float* __restrict__ h, float* __restrict__ rout) {
    int b = blockIdx.x;
    int f = threadIdx.x & 255, c = threadIdx.x >> 8;   // 1024 threads: 4 row-chunks
    const float* hb = h + (size_t)b * NROWS * NH;
    float mx = -1e30f, sm = 0.f;
    for (int p = c; p < NROWS; p += 4) {
        float v = hb[(size_t)p * NH + f];
        mx = fmaxf(mx, v);
        sm += v;
    }
    __shared__ float rm[4][256], rs[4][256];
    rm[c][f] = mx; rs[c][f] = sm;
    __syncthreads();
    if (c == 0) {
        #pragma unroll
        for (int j = 1; j < 4; ++j) { mx = fmaxf(mx, rm[j][f]); sm += rs[j][f]; }
        float rmv = fmaxf(mx, 0.f);
        float rav = fmaxf(sm * (1.0f / NROWS), 0.f);
        if (INIT) { rout[b * 512 + f] = rmv;  rout[b * 512 + NH + f] = rav; }
        else      { rout[b * 512 + f] += rmv; rout[b * 512 + NH + f] += rav; }
    }
}

// ---------------- fused stage-3: h3 = relu(0.5*(a2@t3 + t3) + b3) -> readout += ----------------
__global__ __launch_bounds__(256, 2)
void gcn3_fused_kernel(const float* __restrict__ a2, const float* __restrict__ t3,
                       const float* __restrict__ b3, float* __restrict__ rout) {
    constexpr int KC = 16;
    __shared__ float sa[KC][260];            // padded: conflict-free staging
    __shared__ float st[KC][32];
    int b = blockIdx.x >> 3;
    int cb = (blockIdx.x & 7) * 32;
    int tid = threadIdx.x;
    int ct = tid & 7, rt = tid >> 3;
    int c0 = cb + ct * 4, r0 = rt * 8;
    const float* ab = a2 + (size_t)b * KP2 * KP2;
    const float* tb = t3 + (size_t)b * KP2 * NH;
    float acc[8][4] = {};
    for (int q0 = 0; q0 < KP2; q0 += KC) {
        const float4* A4 = (const float4*)ab;
        for (int i = tid; i < 256 * (KC / 4); i += 256) {
            int r = i >> 2, j = i & 3;
            float4 v = A4[(size_t)r * 64 + q0 / 4 + j];
            sa[j * 4 + 0][r] = v.x; sa[j * 4 + 1][r] = v.y;
            sa[j * 4 + 2][r] = v.z; sa[j * 4 + 3][r] = v.w;
        }
        if (tid < KC * 8) {
            int q = tid >> 3, c4 = tid & 7;
            *(float4*)&st[q][c4 * 4] = *(const float4*)&tb[(size_t)(q0 + q) * NH + cb + c4 * 4];
        }
        __syncthreads();
        #pragma unroll
        for (int q = 0; q < KC; ++q) {
            float tv[4], av[8];
            *(float4*)&tv[0] = *(const float4*)&st[q][ct * 4];
            *(float4*)&av[0] = *(const float4*)&sa[q][r0];
            *(float4*)&av[4] = *(const float4*)&sa[q][r0 + 4];
            #pragma unroll
            for (int r = 0; r < 8; ++r)
                #pragma unroll
                for (int c = 0; c < 4; ++c)
                    acc[r][c] += av[r] * tv[c];
        }
        __syncthreads();
    }
    float bv[4];
    *(float4*)&bv[0] = *(const float4*)&b3[c0];
    float mx[4] = {-1e30f, -1e30f, -1e30f, -1e30f}, sm[4] = {};
    for (int r = 0; r < 8; ++r) {
        float4 t4 = *(const float4*)&tb[(size_t)(r0 + r) * NH + c0];
        float tvv[4] = {t4.x, t4.y, t4.z, t4.w};
        #pragma unroll
        for (int c = 0; c < 4; ++c) {
            float h = fmaxf(0.5f * (acc[r][c] + tvv[c]) + bv[c], 0.f);
            mx[c] = fmaxf(mx[c], h);
            sm[c] += h;
        }
    }
    __shared__ float rmx[32][33], rsm[32][33];
    #pragma unroll
    for (int c = 0; c < 4; ++c) { rmx[ct * 4 + c][rt] = mx[c]; rsm[ct * 4 + c][rt] = sm[c]; }
    __syncthreads();
    if (tid < 32) {
        float m = -1e30f, s = 0.f;
        for (int r = 0; r < 32; ++r) { m = fmaxf(m, rmx[tid][r]); s += rsm[tid][r]; }
        rout[b * 512 + cb + tid] += fmaxf(m, 0.f);
        rout[b * 512 + NH + cb + tid] += fmaxf(s * (1.f / KP2), 0.f);
    }
}

// ---------------- final linear (parallel over f-chunks) ----------------
__global__ __launch_bounds__(256)
void final_kernel(const float* __restrict__ rout, const float* __restrict__ Wlin,
                  const float* __restrict__ blin, float* __restrict__ out) {
    int b = blockIdx.x;
    int tid = threadIdx.x;
    int c = tid & 15, fg = tid >> 4;         // 16 f-groups x 16 (10 used) cols
    float acc = 0.f;
    if (c < NCLS) {
        for (int k = 0; k < 32; ++k) {
            int f = fg * 32 + k;
            acc += rout[b * 512 + f] * Wlin[f * NCLS + c];
        }
    }
    __shared__ float red[16][16];
    red[fg][c] = acc;
    __syncthreads();
    if (tid < 16 && c < NCLS) {
        float a = blin[c];
        #pragma unroll
        for (int k = 0; k < 16; ++k) a += red[k][c];
        out[b * NCLS + c] = a;
    }
}

extern "C" void kernel_launch(void* const* d_in, const int* in_sizes, int n_in,
                              void* d_out, int out_size, void* d_ws, size_t ws_size,
                              hipStream_t stream) {
    const float* x    = (const float*)d_in[0];
    const float* adj  = (const float*)d_in[1];
    const float* W1   = (const float*)d_in[2];
    const float* b1   = (const float*)d_in[3];
    const float* W2   = (const float*)d_in[4];
    const float* b2   = (const float*)d_in[5];
    const float* W3   = (const float*)d_in[6];
    const float* b3   = (const float*)d_in[7];
    const float* att1 = (const float*)d_in[8];
    const float* att2 = (const float*)d_in[9];
    const float* Wlin = (const float*)d_in[10];
    const float* blin = (const float*)d_in[11];
    float* out = (float*)d_out;

    float* fws = (float*)d_ws;
    float* t1  = fws;                        // 8,388,608 floats
    float* h1  = t1 + 8388608;               // 8,388,608
    float* hk  = h1 + 8388608;               // 4,194,304
    float* dgi = hk + 4194304;               // 32768
    float* dia = dgi + 32768;                // 32768
    float* sc  = dia + 32768;                // 32768
    float* lv  = sc + 32768;                 // 16384
    float* rv  = lv + 16384;                 // 16384
    float* rout = rv + 16384;                // 16384
    float* v1  = rout + 16384;               // 16384
    float* V1  = v1 + 16384;                 // 64 (padded)
    float* Z1  = V1 + 64;                    // 16384
    float* wp  = Z1 + 16384;                 // 32*8*256 = 65536
    int* cnt  = (int*)(wp + 65536);          // 32768
    int* nbr  = cnt + 32768;                 // 32768*64 = 2,097,152
    int* idx1 = nbr + 32768 * MAXD;          // 16384
    int* idx2 = idx1 + 16384;                // 8192
    int* pos1 = idx2 + 8192;                 // 32768
    // aliases (lifetime-disjoint reuse)
    float* t2   = h1;                        // stage-2 XW   [B*KP1*NH]
    float* h2   = h1 + 4194304;              // stage-2 hidden
    float* h2k  = hk;                        // stage-2 pooled rows
    float* a2   = t1;                        // [B*KP2*KP2] = 2,097,152 (t1 dead after gcn1)
    float* t3   = t1 + 2097152;              // 2,097,152
    int*   knbr = (int*)(t1 + 6291456);      // 16384*64 = 1,048,576 ints
    int*   kcnt = knbr + 16384 * MAXD;       // 16384

    // ---- stage 1 (sparse binary graph) ----
    gemm_kernel<FIN><<<1024, 256, 0, stream>>>(x, W1, t1);
    csr_kernel<<<B * N1, 256, 0, stream>>>(adj, cnt, nbr, dgi, dia);
    gcn1_kernel<<<B * N1, 256, 0, stream>>>(t1, cnt, nbr, dgi, b1, h1);
    info1_kernel<<<B * N1, 256, 0, stream>>>(h1, cnt, nbr, dia, sc);
    topk_kernel<N1, KP1, 512, true><<<B, 512, 0, stream>>>(sc, idx1, pos1);
    gather_att_kernel<<<B * KP1, 256, 0, stream>>>(h1, idx1, att1, hk, lv, rv, KP1, N1);
    readout_kernel<KP1, true><<<B, 1024, 0, stream>>>(hk, rout);

    // ---- pool-1 factorization: a1[p,q] = v_q*(1+E1*adjk)/Z_p ----
    vexp_kernel<<<B, 512, 0, stream>>>(rv, v1, V1);
    knbr_kernel<<<B * KP1, 64, 0, stream>>>(idx1, cnt, nbr, pos1, v1, V1, knbr, kcnt, Z1);

    // ---- stage 2 (factorized a1) ----
    gemm_kernel<NH><<<512, 256, 0, stream>>>(hk, W2, t2);
    wsum_kernel<<<B * 8, 256, 0, stream>>>(t2, v1, wp);
    gcn2_kernel<<<B * KP1, 256, 0, stream>>>(t2, wp, v1, Z1, knbr, kcnt, b2, h2);
    wsum_kernel<<<B * 8, 256, 0, stream>>>(h2, v1, wp);
    info2_kernel<<<B * KP1, 256, 0, stream>>>(h2, wp, v1, Z1, knbr, kcnt, sc);
    topk_kernel<KP1, KP2, 512, false><<<B, 512, 0, stream>>>(sc, idx2, nullptr);
    gather_att_kernel<<<B * KP2, 256, 0, stream>>>(h2, idx2, att2, h2k, lv, rv, KP2, KP1);
    readout_kernel<KP2, false><<<B, 1024, 0, stream>>>(h2k, rout);
    a2_kernel<<<B * KP2, 256, 0, stream>>>(idx2, rv, v1, Z1, knbr, kcnt, a2);

    // ---- stage 3 (fused dense GCN + readout) ----
    gemm_kernel<NH><<<256, 256, 0, stream>>>(h2k, W3, t3);
    gcn3_fused_kernel<<<B * 8, 256, 0, stream>>>(a2, t3, b3, rout);

    // ---- classifier ----
    final_kernel<<<B, 256, 0, stream>>>(rout, Wlin, blin, out);
}

// Round 7
// 341.680 us; speedup vs baseline: 2.2318x; 1.3540x over previous
//
#include <hip/hip_runtime.h>

#define B    32
#define N1   1024
#define FIN  128
#define NH   256
#define KP1  512
#define KP2  256
#define NCLS 10
#define MAXD 64
#define E1   1.7182818284590452f   // e^LAMB - 1, LAMB = 1.0

typedef float4 F4;
__device__ __forceinline__ void fma4(F4& a, float s, F4 v) {
    a.x += s * v.x; a.y += s * v.y; a.z += s * v.z; a.w += s * v.w;
}
__device__ __forceinline__ void add4(F4& a, F4 v) {
    a.x += v.x; a.y += v.y; a.z += v.z; a.w += v.w;
}
__device__ __forceinline__ void max4(F4& a, F4 v) {
    a.x = fmaxf(a.x, v.x); a.y = fmaxf(a.y, v.y); a.z = fmaxf(a.z, v.z); a.w = fmaxf(a.w, v.w);
}

// ---------------- tiled GEMM: out[M,256] = A[M,KD] @ W[KD,256], BM=32, KC=32 ----------------
template<int KD>
__global__ __launch_bounds__(256, 3)
void gemm_kernel(const float* __restrict__ A, const float* __restrict__ W,
                 float* __restrict__ out) {
    constexpr int KC = 32;
    constexpr int BM = 32, TM = 4;
    __shared__ float sw[KC][256];
    __shared__ float sa[KC][BM + 4];
    int m0 = blockIdx.x * BM;
    int tid = threadIdx.x;
    int ct = tid & 31, rt = tid >> 5;
    int c0 = ct * 8, r0 = rt * TM;
    float acc[TM][8] = {};
    for (int q0 = 0; q0 < KD; q0 += KC) {
        const float4* W4 = (const float4*)(W + q0 * 256);
        for (int i = tid; i < KC * 64; i += 256) {
            int q = i >> 6, c4 = i & 63;
            *(float4*)&sw[q][c4 * 4] = W4[q * 64 + c4];
        }
        const float4* A4 = (const float4*)A;
        for (int i = tid; i < BM * (KC / 4); i += 256) {
            int r = i / (KC / 4), j = i % (KC / 4);
            float4 v = A4[(size_t)(m0 + r) * (KD / 4) + q0 / 4 + j];
            sa[j * 4 + 0][r] = v.x; sa[j * 4 + 1][r] = v.y;
            sa[j * 4 + 2][r] = v.z; sa[j * 4 + 3][r] = v.w;
        }
        __syncthreads();
        #pragma unroll
        for (int q = 0; q < KC; ++q) {
            float wv[8], av[TM];
            *(float4*)&wv[0] = *(const float4*)&sw[q][c0];
            *(float4*)&wv[4] = *(const float4*)&sw[q][c0 + 4];
            *(float4*)&av[0] = *(const float4*)&sa[q][r0];
            #pragma unroll
            for (int r = 0; r < TM; ++r)
                #pragma unroll
                for (int c = 0; c < 8; ++c)
                    acc[r][c] += av[r] * wv[c];
        }
        __syncthreads();
    }
    for (int r = 0; r < TM; ++r) {
        *(float4*)&out[(size_t)(m0 + r0 + r) * 256 + c0] = *(float4*)&acc[r][0];
        *(float4*)&out[(size_t)(m0 + r0 + r) * 256 + c0 + 4] = *(float4*)&acc[r][4];
    }
}

// ---------------- CSR build: wave-scan prefix, deterministic (column-ordered) ----------------
__global__ __launch_bounds__(256)
void csr_kernel(const float* __restrict__ adj, int* __restrict__ cnt,
                int* __restrict__ nbr, float* __restrict__ dgi,
                float* __restrict__ dia) {
    int row = blockIdx.x;                    // b*N1 + i
    const float* arow = adj + (size_t)row * N1;
    int t = threadIdx.x, lane = t & 63, wave = t >> 6;
    float4 v4 = ((const float4*)arow)[t];
    int loc[4];
    int c = 0;
    if (v4.x > 0.5f) loc[c++] = t * 4 + 0;
    if (v4.y > 0.5f) loc[c++] = t * 4 + 1;
    if (v4.z > 0.5f) loc[c++] = t * 4 + 2;
    if (v4.w > 0.5f) loc[c++] = t * 4 + 3;
    int x = c;
    #pragma unroll
    for (int s = 1; s < 64; s <<= 1) {
        int y = __shfl_up(x, s);
        if (lane >= s) x += y;
    }
    __shared__ int wtot[4];
    if (lane == 63) wtot[wave] = x;
    __syncthreads();
    int base = 0;
    #pragma unroll
    for (int w = 0; w < 4; ++w) base += (w < wave) ? wtot[w] : 0;
    int total = wtot[0] + wtot[1] + wtot[2] + wtot[3];
    int off = base + x - c;                  // exclusive prefix in column order
    for (int u = 0; u < c; ++u) {
        int p = off + u;
        if (p < MAXD) nbr[(size_t)row * MAXD + p] = loc[u];
    }
    if (t == 0) {
        cnt[row] = min(total, MAXD);
        dgi[row] = rsqrtf((float)total + 1.0f);            // deg of A=adj+I
        dia[row] = total > 0 ? 1.0f / (float)total : 0.0f; // deg of adj
    }
}

// ---------------- stage-1 GCN aggregate: wave-per-row, float4, shfl-broadcast ----------------
__global__ __launch_bounds__(256)
void gcn1_kernel(const float* __restrict__ t1, const int* __restrict__ cnt,
                 const int* __restrict__ nbr, const float* __restrict__ dgi,
                 const float* __restrict__ b1, float* __restrict__ h1) {
    int blk = blockIdx.x;                    // 32 b x 256 groups
    int b = blk & 31, g = blk >> 5;
    int lane = threadIdx.x & 63, wave = threadIdx.x >> 6;
    int i = g * 4 + wave;
    int row = (b << 10) + i;
    const F4* tb = (const F4*)(t1 + (((size_t)b << 10)) * NH);
    int n = cnt[row];
    int jv = 0; float dv = 0.f;
    if (lane < n) {
        jv = nbr[(size_t)row * MAXD + lane];
        dv = dgi[(b << 10) + jv];
    }
    F4 a0 = make_float4(0,0,0,0), a1 = a0, a2 = a0, a3 = a0;
    int e = 0;
    for (; e + 4 <= n; e += 4) {
        int j0 = __shfl(jv, e), j1 = __shfl(jv, e+1), j2 = __shfl(jv, e+2), j3 = __shfl(jv, e+3);
        float d0 = __shfl(dv, e), d1 = __shfl(dv, e+1), d2 = __shfl(dv, e+2), d3 = __shfl(dv, e+3);
        F4 v0 = tb[(size_t)j0 * 64 + lane]; F4 v1 = tb[(size_t)j1 * 64 + lane];
        F4 v2 = tb[(size_t)j2 * 64 + lane]; F4 v3 = tb[(size_t)j3 * 64 + lane];
        fma4(a0, d0, v0); fma4(a1, d1, v1); fma4(a2, d2, v2); fma4(a3, d3, v3);
    }
    for (; e < n; ++e) {
        int j = __shfl(jv, e); float d = __shfl(dv, e);
        fma4(a0, d, tb[(size_t)j * 64 + lane]);
    }
    add4(a0, a1); add4(a2, a3); add4(a0, a2);
    float di = dgi[row];
    F4 self = tb[(size_t)i * 64 + lane];
    F4 bb = ((const F4*)b1)[lane];
    F4 r;
    r.x = fmaxf(di * (a0.x + di * self.x) + bb.x, 0.f);
    r.y = fmaxf(di * (a0.y + di * self.y) + bb.y, 0.f);
    r.z = fmaxf(di * (a0.z + di * self.z) + bb.z, 0.f);
    r.w = fmaxf(di * (a0.w + di * self.w) + bb.w, 0.f);
    ((F4*)(h1 + (size_t)row * NH))[lane] = r;
}

// ---------------- stage-1 info score: wave-per-row, float4 ----------------
__global__ __launch_bounds__(256)
void info1_kernel(const float* __restrict__ h1, const int* __restrict__ cnt,
                  const int* __restrict__ nbr, const float* __restrict__ dia,
                  float* __restrict__ sc) {
    int blk = blockIdx.x;
    int b = blk & 31, g = blk >> 5;
    int lane = threadIdx.x & 63, wave = threadIdx.x >> 6;
    int i = g * 4 + wave;
    int row = (b << 10) + i;
    const F4* hb = (const F4*)(h1 + (((size_t)b << 10)) * NH);
    int n = cnt[row];
    int jv = 0;
    if (lane < n) jv = nbr[(size_t)row * MAXD + lane];
    F4 a0 = make_float4(0,0,0,0), a1 = a0, a2 = a0, a3 = a0;
    int e = 0;
    for (; e + 4 <= n; e += 4) {
        int j0 = __shfl(jv, e), j1 = __shfl(jv, e+1), j2 = __shfl(jv, e+2), j3 = __shfl(jv, e+3);
        add4(a0, hb[(size_t)j0 * 64 + lane]); add4(a1, hb[(size_t)j1 * 64 + lane]);
        add4(a2, hb[(size_t)j2 * 64 + lane]); add4(a3, hb[(size_t)j3 * 64 + lane]);
    }
    for (; e < n; ++e) {
        int j = __shfl(jv, e);
        add4(a0, hb[(size_t)j * 64 + lane]);
    }
    add4(a0, a1); add4(a2, a3); add4(a0, a2);
    float dd = dia[row];
    F4 self = hb[(size_t)i * 64 + lane];
    float val = fabsf(self.x - dd * a0.x) + fabsf(self.y - dd * a0.y)
              + fabsf(self.z - dd * a0.z) + fabsf(self.w - dd * a0.w);
    val += __shfl_xor(val, 32); val += __shfl_xor(val, 16);
    val += __shfl_xor(val, 8);  val += __shfl_xor(val, 4);
    val += __shfl_xor(val, 2);  val += __shfl_xor(val, 1);
    if (lane == 0) sc[row] = val;
}

// ---------------- top-k via bitonic sort (desc, tie: lower index first) ----------------
template<int NS, int KS, int NT, bool POS>
__global__ __launch_bounds__(512)
void topk_kernel(const float* __restrict__ sc, int* __restrict__ idxo,
                 int* __restrict__ pos) {
    int b = blockIdx.x;
    __shared__ float s[NS];
    __shared__ int id[NS];
    for (int i = threadIdx.x; i < NS; i += NT) { s[i] = sc[b * NS + i]; id[i] = i; }
    __syncthreads();
    for (int ksz = 2; ksz <= NS; ksz <<= 1) {
        for (int j = ksz >> 1; j > 0; j >>= 1) {
            for (int i = threadIdx.x; i < NS; i += NT) {
                int l = i ^ j;
                if (l > i) {
                    float si = s[i], sl = s[l];
                    int ii = id[i], il = id[l];
                    bool iBeforeL = (si > sl) || (si == sl && ii < il);
                    bool dirDesc = ((i & ksz) == 0);
                    if (dirDesc ? !iBeforeL : iBeforeL) {
                        s[i] = sl; s[l] = si; id[i] = il; id[l] = ii;
                    }
                }
            }
            __syncthreads();
        }
    }
    for (int t = threadIdx.x; t < KS; t += NT) idxo[b * KS + t] = id[t];
    if (POS)
        for (int t = threadIdx.x; t < NS; t += NT)
            pos[b * NS + id[t]] = (t < KS) ? t : -1;
}

// ---------------- gather pooled rows + attention dots: wave-per-row ----------------
__global__ __launch_bounds__(256)
void gather_att_kernel(const float* __restrict__ h, const int* __restrict__ idx,
                       const float* __restrict__ att, float* __restrict__ hk,
                       float* __restrict__ lv, float* __restrict__ rv,
                       int K, int Nsrc) {
    int blk = blockIdx.x;                    // 32 b x (K/4) groups
    int b = blk & 31, g = blk >> 5;
    int lane = threadIdx.x & 63, wave = threadIdx.x >> 6;
    int p = g * 4 + wave;
    int gg = b * K + p;
    int src = idx[gg];
    F4 v = ((const F4*)(h + ((size_t)b * Nsrc + src) * NH))[lane];
    ((F4*)(hk + (size_t)gg * NH))[lane] = v;
    F4 al = ((const F4*)att)[lane];
    F4 ar = ((const F4*)att)[64 + lane];
    float r1 = v.x * al.x + v.y * al.y + v.z * al.z + v.w * al.w;
    float r2 = v.x * ar.x + v.y * ar.y + v.z * ar.z + v.w * ar.w;
    r1 += __shfl_xor(r1, 32); r2 += __shfl_xor(r2, 32);
    r1 += __shfl_xor(r1, 16); r2 += __shfl_xor(r2, 16);
    r1 += __shfl_xor(r1, 8);  r2 += __shfl_xor(r2, 8);
    r1 += __shfl_xor(r1, 4);  r2 += __shfl_xor(r2, 4);
    r1 += __shfl_xor(r1, 2);  r2 += __shfl_xor(r2, 2);
    r1 += __shfl_xor(r1, 1);  r2 += __shfl_xor(r2, 1);
    if (lane == 0) { lv[gg] = r1; rv[gg] = r2; }
}

// ---------------- v = exp(r - rowmax), V = sum v (per batch) ----------------
__global__ __launch_bounds__(512)
void vexp_kernel(const float* __restrict__ rv, float* __restrict__ v1,
                 float* __restrict__ V1) {
    int b = blockIdx.x;
    int t = threadIdx.x;             // 512
    __shared__ float red[512];
    float r = rv[b * KP1 + t];
    red[t] = r;
    __syncthreads();
    for (int s = 256; s > 0; s >>= 1) {
        if (t < s) red[t] = fmaxf(red[t], red[t + s]);
        __syncthreads();
    }
    float mx = red[0];
    __syncthreads();
    float v = expf(r - mx);
    v1[b * KP1 + t] = v;
    red[t] = v;
    __syncthreads();
    for (int s = 256; s > 0; s >>= 1) {
        if (t < s) red[t] += red[t + s];
        __syncthreads();
    }
    if (t == 0) V1[b] = red[0];
}

// ---------------- induced-subgraph CSR on idx1 + Z1 (XCD-clustered) ----------------
__global__ __launch_bounds__(64)
void knbr_kernel(const int* __restrict__ idx1, const int* __restrict__ cnt,
                 const int* __restrict__ nbr, const int* __restrict__ pos1,
                 const float* __restrict__ v1, const float* __restrict__ V1,
                 int* __restrict__ knbr, int* __restrict__ kcnt,
                 float* __restrict__ Z1) {
    int j = blockIdx.x;
    int b = j & 31, p = j >> 5;
    int g = b * KP1 + p;
    int lane = threadIdx.x;          // 64 = one wave
    int ip = idx1[g];
    int n = cnt[b * N1 + ip];
    int q = -1;
    if (lane < n) {
        int jj = nbr[(size_t)(b * N1 + ip) * MAXD + lane];
        q = pos1[b * N1 + jj];
    }
    bool kept = q >= 0;
    unsigned long long mask = __ballot(kept);
    int off = __popcll(mask & ((1ull << lane) - 1ull));
    if (kept) knbr[(size_t)g * MAXD + off] = q;
    float s = kept ? v1[b * KP1 + q] : 0.f;
    for (int o = 32; o > 0; o >>= 1) s += __shfl_down(s, o);
    if (lane == 0) { kcnt[g] = __popcll(mask); Z1[g] = V1[b] + E1 * s; }
}

// ---------------- per-batch weighted column sum (partials over 8 chunks) ----------------
__global__ __launch_bounds__(256)
void wsum_kernel(const float* __restrict__ X, const float* __restrict__ v1,
                 float* __restrict__ wp) {
    int blk = blockIdx.x;            // b*8 + c
    int b = blk >> 3, c = blk & 7;
    int f = threadIdx.x;
    float a0 = 0.f, a1 = 0.f, a2 = 0.f, a3 = 0.f;
    for (int q = c * 64; q < c * 64 + 64; q += 4) {
        a0 += v1[b * KP1 + q + 0] * X[(size_t)(b * KP1 + q + 0) * NH + f];
        a1 += v1[b * KP1 + q + 1] * X[(size_t)(b * KP1 + q + 1) * NH + f];
        a2 += v1[b * KP1 + q + 2] * X[(size_t)(b * KP1 + q + 2) * NH + f];
        a3 += v1[b * KP1 + q + 3] * X[(size_t)(b * KP1 + q + 3) * NH + f];
    }
    wp[(size_t)blk * NH + f] = (a0 + a1) + (a2 + a3);
}

// ---------------- stage-2 GCN via factorized a1: wave-per-row ----------------
__global__ __launch_bounds__(256)
void gcn2_kernel(const float* __restrict__ t2, const float* __restrict__ wp,
                 const float* __restrict__ v1, const float* __restrict__ Z1,
                 const int* __restrict__ knbr, const int* __restrict__ kcnt,
                 const float* __restrict__ b2, float* __restrict__ h2) {
    int blk = blockIdx.x;                    // 32 b x 128 groups
    int b = blk & 31, g = blk >> 5;
    int lane = threadIdx.x & 63, wave = threadIdx.x >> 6;
    int p = g * 4 + wave;
    int gg = (b << 9) + p;
    const F4* tb = (const F4*)(t2 + (((size_t)b << 9)) * NH);
    int n = kcnt[gg];
    int jv = 0; float wv = 0.f;
    if (lane < n) {
        jv = knbr[(size_t)gg * MAXD + lane];
        wv = v1[(b << 9) + jv];
    }
    F4 a0 = make_float4(0,0,0,0), a1 = a0, a2 = a0, a3 = a0;
    int e = 0;
    for (; e + 4 <= n; e += 4) {
        int j0 = __shfl(jv, e), j1 = __shfl(jv, e+1), j2 = __shfl(jv, e+2), j3 = __shfl(jv, e+3);
        float d0 = __shfl(wv, e), d1 = __shfl(wv, e+1), d2 = __shfl(wv, e+2), d3 = __shfl(wv, e+3);
        fma4(a0, d0, tb[(size_t)j0 * 64 + lane]); fma4(a1, d1, tb[(size_t)j1 * 64 + lane]);
        fma4(a2, d2, tb[(size_t)j2 * 64 + lane]); fma4(a3, d3, tb[(size_t)j3 * 64 + lane]);
    }
    for (; e < n; ++e) {
        int j = __shfl(jv, e); float d = __shfl(wv, e);
        fma4(a0, d, tb[(size_t)j * 64 + lane]);
    }
    add4(a0, a1); add4(a2, a3); add4(a0, a2);
    F4 w = make_float4(0,0,0,0);
    #pragma unroll
    for (int c = 0; c < 8; ++c) add4(w, ((const F4*)wp)[(size_t)(b * 8 + c) * 64 + lane]);
    float zi = 1.0f / Z1[gg];
    F4 tv = tb[(size_t)p * 64 + lane];
    F4 bb = ((const F4*)b2)[lane];
    F4 r;
    r.x = fmaxf(0.5f * ((w.x + E1 * a0.x) * zi + tv.x) + bb.x, 0.f);
    r.y = fmaxf(0.5f * ((w.y + E1 * a0.y) * zi + tv.y) + bb.y, 0.f);
    r.z = fmaxf(0.5f * ((w.z + E1 * a0.z) * zi + tv.z) + bb.z, 0.f);
    r.w = fmaxf(0.5f * ((w.w + E1 * a0.w) * zi + tv.w) + bb.w, 0.f);
    ((F4*)(h2 + (size_t)gg * NH))[lane] = r;
}

// ---------------- stage-2 info score via factorized a1: wave-per-row ----------------
__global__ __launch_bounds__(256)
void info2_kernel(const float* __restrict__ h2, const float* __restrict__ wp,
                  const float* __restrict__ v1, const float* __restrict__ Z1,
                  const int* __restrict__ knbr, const int* __restrict__ kcnt,
                  float* __restrict__ sc) {
    int blk = blockIdx.x;
    int b = blk & 31, g = blk >> 5;
    int lane = threadIdx.x & 63, wave = threadIdx.x >> 6;
    int p = g * 4 + wave;
    int gg = (b << 9) + p;
    const F4* hb = (const F4*)(h2 + (((size_t)b << 9)) * NH);
    int n = kcnt[gg];
    int jv = 0; float wv = 0.f;
    if (lane < n) {
        jv = knbr[(size_t)gg * MAXD + lane];
        wv = v1[(b << 9) + jv];
    }
    F4 a0 = make_float4(0,0,0,0), a1 = a0, a2 = a0, a3 = a0;
    int e = 0;
    for (; e + 4 <= n; e += 4) {
        int j0 = __shfl(jv, e), j1 = __shfl(jv, e+1), j2 = __shfl(jv, e+2), j3 = __shfl(jv, e+3);
        float d0 = __shfl(wv, e), d1 = __shfl(wv, e+1), d2 = __shfl(wv, e+2), d3 = __shfl(wv, e+3);
        fma4(a0, d0, hb[(size_t)j0 * 64 + lane]); fma4(a1, d1, hb[(size_t)j1 * 64 + lane]);
        fma4(a2, d2, hb[(size_t)j2 * 64 + lane]); fma4(a3, d3, hb[(size_t)j3 * 64 + lane]);
    }
    for (; e < n; ++e) {
        int j = __shfl(jv, e); float d = __shfl(wv, e);
        fma4(a0, d, hb[(size_t)j * 64 + lane]);
    }
    add4(a0, a1); add4(a2, a3); add4(a0, a2);
    F4 w = make_float4(0,0,0,0);
    #pragma unroll
    for (int c = 0; c < 8; ++c) add4(w, ((const F4*)wp)[(size_t)(b * 8 + c) * 64 + lane]);
    float zi = 1.0f / Z1[gg];
    F4 self = hb[(size_t)p * 64 + lane];
    float val = fabsf(self.x - (w.x + E1 * a0.x) * zi) + fabsf(self.y - (w.y + E1 * a0.y) * zi)
              + fabsf(self.z - (w.z + E1 * a0.z) * zi) + fabsf(self.w - (w.w + E1 * a0.w) * zi);
    val += __shfl_xor(val, 32); val += __shfl_xor(val, 16);
    val += __shfl_xor(val, 8);  val += __shfl_xor(val, 4);
    val += __shfl_xor(val, 2);  val += __shfl_xor(val, 1);
    if (lane == 0) sc[gg] = val;
}

// ---------------- materialize a2 = softmax(r2_q + a1k[p,q]) (XCD-clustered) ----------------
__global__ __launch_bounds__(256)
void a2_kernel(const int* __restrict__ idx2, const float* __restrict__ rv,
               const float* __restrict__ v1, const float* __restrict__ Z1,
               const int* __restrict__ knbr, const int* __restrict__ kcnt,
               float* __restrict__ a2) {
    int j = blockIdx.x;
    int b = j & 31, p = j >> 5;
    int g = b * KP2 + p;
    int q = threadIdx.x;             // 256
    int p2 = idx2[g];                // position in [0,KP1)
    int gp = b * KP1 + p2;
    __shared__ unsigned char flag[KP1];
    flag[q] = 0; flag[q + 256] = 0;
    __syncthreads();
    int n = kcnt[gp];
    if (q < n) flag[knbr[(size_t)gp * MAXD + q]] = 1;
    __syncthreads();
    int q2 = idx2[b * KP2 + q];
    float a1k = v1[b * KP1 + q2] * (flag[q2] ? (1.f + E1) : 1.f) / Z1[gp];
    float z = rv[b * KP2 + q] + a1k;       // l_p cancels in softmax
    __shared__ float red[256];
    red[q] = z;
    __syncthreads();
    for (int s = 128; s > 0; s >>= 1) {
        if (q < s) red[q] = fmaxf(red[q], red[q + s]);
        __syncthreads();
    }
    float mx = red[0];
    __syncthreads();
    float e = expf(z - mx);
    red[q] = e;
    __syncthreads();
    for (int s = 128; s > 0; s >>= 1) {
        if (q < s) red[q] += red[q + s];
        __syncthreads();
    }
    a2[(size_t)g * KP2 + q] = e / red[0];
}

// ---------------- readout: 256 blocks (b x 8 col-chunks) ----------------
template<int NROWS, bool INIT>
__global__ __launch_bounds__(256)
void readout_kernel(const float* __restrict__ h, float* __restrict__ rout) {
    int blk = blockIdx.x;
    int b = blk & 31, ch = blk >> 5;         // 8 chunks x 8 f4-cols
    int c = threadIdx.x & 7, rg = threadIdx.x >> 3;   // 8 f4-cols x 32 row-groups
    int f4 = ch * 8 + c;
    const F4* hb = (const F4*)(h + (size_t)b * NROWS * NH);
    F4 mx = make_float4(-1e30f, -1e30f, -1e30f, -1e30f);
    F4 sm = make_float4(0, 0, 0, 0);
    for (int r = rg; r < NROWS; r += 32) {
        F4 v = hb[(size_t)r * 64 + f4];
        max4(mx, v); add4(sm, v);
    }
    __shared__ F4 rmx[32][9], rsm[32][9];
    rmx[rg][c] = mx; rsm[rg][c] = sm;
    __syncthreads();
    for (int s = 16; s > 0; s >>= 1) {
        if (rg < s) {
            F4 m2 = rmx[rg + s][c], s2 = rsm[rg + s][c];
            max4(rmx[rg][c], m2); add4(rsm[rg][c], s2);
            rmx[rg][c] = rmx[rg][c]; rsm[rg][c] = rsm[rg][c];
        }
        __syncthreads();
    }
    if (rg == 0) {
        F4 m = rmx[0][c], s4 = rsm[0][c];
        F4 rm, ra;
        rm.x = fmaxf(m.x, 0.f); rm.y = fmaxf(m.y, 0.f); rm.z = fmaxf(m.z, 0.f); rm.w = fmaxf(m.w, 0.f);
        const float inv = 1.0f / NROWS;
        ra.x = fmaxf(s4.x * inv, 0.f); ra.y = fmaxf(s4.y * inv, 0.f);
        ra.z = fmaxf(s4.z * inv, 0.f); ra.w = fmaxf(s4.w * inv, 0.f);
        F4* ro = (F4*)(rout + b * 512);
        if (INIT) {
            ro[f4] = rm; ro[64 + f4] = ra;
        } else {
            F4 o1 = ro[f4], o2 = ro[64 + f4];
            add4(o1, rm); add4(o2, ra);
            ro[f4] = o1; ro[64 + f4] = o2;
        }
    }
}

// ---------------- fused stage-3: h3 = relu(0.5*(a2@t3 + t3) + b3) -> readout += ----------------
__global__ __launch_bounds__(256, 2)
void gcn3_fused_kernel(const float* __restrict__ a2, const float* __restrict__ t3,
                       const float* __restrict__ b3, float* __restrict__ rout) {
    constexpr int KC = 16;
    __shared__ float sa[KC][260];            // padded: conflict-free staging
    __shared__ float st[KC][32];
    int b = blockIdx.x >> 3;
    int cb = (blockIdx.x & 7) * 32;
    int tid = threadIdx.x;
    int ct = tid & 7, rt = tid >> 3;
    int c0 = cb + ct * 4, r0 = rt * 8;
    const float* ab = a2 + (size_t)b * KP2 * KP2;
    const float* tb = t3 + (size_t)b * KP2 * NH;
    float acc[8][4] = {};
    for (int q0 = 0; q0 < KP2; q0 += KC) {
        const float4* A4 = (const float4*)ab;
        for (int i = tid; i < 256 * (KC / 4); i += 256) {
            int r = i >> 2, j = i & 3;
            float4 v = A4[(size_t)r * 64 + q0 / 4 + j];
            sa[j * 4 + 0][r] = v.x; sa[j * 4 + 1][r] = v.y;
            sa[j * 4 + 2][r] = v.z; sa[j * 4 + 3][r] = v.w;
        }
        if (tid < KC * 8) {
            int q = tid >> 3, c4 = tid & 7;
            *(float4*)&st[q][c4 * 4] = *(const float4*)&tb[(size_t)(q0 + q) * NH + cb + c4 * 4];
        }
        __syncthreads();
        #pragma unroll
        for (int q = 0; q < KC; ++q) {
            float tv[4], av[8];
            *(float4*)&tv[0] = *(const float4*)&st[q][ct * 4];
            *(float4*)&av[0] = *(const float4*)&sa[q][r0];
            *(float4*)&av[4] = *(const float4*)&sa[q][r0 + 4];
            #pragma unroll
            for (int r = 0; r < 8; ++r)
                #pragma unroll
                for (int c = 0; c < 4; ++c)
                    acc[r][c] += av[r] * tv[c];
        }
        __syncthreads();
    }
    float bv[4];
    *(float4*)&bv[0] = *(const float4*)&b3[c0];
    float mx[4] = {-1e30f, -1e30f, -1e30f, -1e30f}, sm[4] = {};
    for (int r = 0; r < 8; ++r) {
        float4 t4 = *(const float4*)&tb[(size_t)(r0 + r) * NH + c0];
        float tvv[4] = {t4.x, t4.y, t4.z, t4.w};
        #pragma unroll
        for (int c = 0; c < 4; ++c) {
            float h = fmaxf(0.5f * (acc[r][c] + tvv[c]) + bv[c], 0.f);
            mx[c] = fmaxf(mx[c], h);
            sm[c] += h;
        }
    }
    __shared__ float rmx2[32][33], rsm2[32][33];
    #pragma unroll
    for (int c = 0; c < 4; ++c) { rmx2[ct * 4 + c][rt] = mx[c]; rsm2[ct * 4 + c][rt] = sm[c]; }
    __syncthreads();
    if (tid < 32) {
        float m = -1e30f, s = 0.f;
        for (int r = 0; r < 32; ++r) { m = fmaxf(m, rmx2[tid][r]); s += rsm2[tid][r]; }
        rout[b * 512 + cb + tid] += fmaxf(m, 0.f);
        rout[b * 512 + NH + cb + tid] += fmaxf(s * (1.f / KP2), 0.f);
    }
}

// ---------------- final linear (parallel over f-chunks) ----------------
__global__ __launch_bounds__(256)
void final_kernel(const float* __restrict__ rout, const float* __restrict__ Wlin,
                  const float* __restrict__ blin, float* __restrict__ out) {
    int b = blockIdx.x;
    int tid = threadIdx.x;
    int c = tid & 15, fg = tid >> 4;         // 16 f-groups x 16 (10 used) cols
    float acc = 0.f;
    if (c < NCLS) {
        for (int k = 0; k < 32; ++k) {
            int f = fg * 32 + k;
            acc += rout[b * 512 + f] * Wlin[f * NCLS + c];
        }
    }
    __shared__ float red[16][16];
    red[fg][c] = acc;
    __syncthreads();
    if (tid < 16 && c < NCLS) {
        float a = blin[c];
        #pragma unroll
        for (int k = 0; k < 16; ++k) a += red[k][c];
        out[b * NCLS + c] = a;
    }
}

extern "C" void kernel_launch(void* const* d_in, const int* in_sizes, int n_in,
                              void* d_out, int out_size, void* d_ws, size_t ws_size,
                              hipStream_t stream) {
    const float* x    = (const float*)d_in[0];
    const float* adj  = (const float*)d_in[1];
    const float* W1   = (const float*)d_in[2];
    const float* b1   = (const float*)d_in[3];
    const float* W2   = (const float*)d_in[4];
    const float* b2   = (const float*)d_in[5];
    const float* W3   = (const float*)d_in[6];
    const float* b3   = (const float*)d_in[7];
    const float* att1 = (const float*)d_in[8];
    const float* att2 = (const float*)d_in[9];
    const float* Wlin = (const float*)d_in[10];
    const float* blin = (const float*)d_in[11];
    float* out = (float*)d_out;

    float* fws = (float*)d_ws;
    float* t1  = fws;                        // 8,388,608 floats
    float* h1  = t1 + 8388608;               // 8,388,608
    float* hk  = h1 + 8388608;               // 4,194,304
    float* dgi = hk + 4194304;               // 32768
    float* dia = dgi + 32768;                // 32768
    float* sc  = dia + 32768;                // 32768
    float* lv  = sc + 32768;                 // 16384
    float* rv  = lv + 16384;                 // 16384
    float* rout = rv + 16384;                // 16384
    float* v1  = rout + 16384;               // 16384
    float* V1  = v1 + 16384;                 // 64 (padded)
    float* Z1  = V1 + 64;                    // 16384
    float* wp  = Z1 + 16384;                 // 32*8*256 = 65536
    int* cnt  = (int*)(wp + 65536);          // 32768
    int* nbr  = cnt + 32768;                 // 32768*64 = 2,097,152
    int* idx1 = nbr + 32768 * MAXD;          // 16384
    int* idx2 = idx1 + 16384;                // 8192
    int* pos1 = idx2 + 8192;                 // 32768
    // aliases (lifetime-disjoint reuse)
    float* t2   = h1;                        // stage-2 XW   [B*KP1*NH]
    float* h2   = h1 + 4194304;              // stage-2 hidden
    float* h2k  = hk;                        // stage-2 pooled rows
    float* a2   = t1;                        // [B*KP2*KP2] = 2,097,152 (t1 dead after gcn1)
    float* t3   = t1 + 2097152;              // 2,097,152
    int*   knbr = (int*)(t1 + 6291456);      // 16384*64 = 1,048,576 ints
    int*   kcnt = knbr + 16384 * MAXD;       // 16384

    // ---- stage 1 (sparse binary graph) ----
    gemm_kernel<FIN><<<1024, 256, 0, stream>>>(x, W1, t1);
    csr_kernel<<<B * N1, 256, 0, stream>>>(adj, cnt, nbr, dgi, dia);
    gcn1_kernel<<<B * 256, 256, 0, stream>>>(t1, cnt, nbr, dgi, b1, h1);
    info1_kernel<<<B * 256, 256, 0, stream>>>(h1, cnt, nbr, dia, sc);
    topk_kernel<N1, KP1, 512, true><<<B, 512, 0, stream>>>(sc, idx1, pos1);
    gather_att_kernel<<<B * 128, 256, 0, stream>>>(h1, idx1, att1, hk, lv, rv, KP1, N1);
    readout_kernel<KP1, true><<<256, 256, 0, stream>>>(hk, rout);

    // ---- pool-1 factorization: a1[p,q] = v_q*(1+E1*adjk)/Z_p ----
    vexp_kernel<<<B, 512, 0, stream>>>(rv, v1, V1);
    knbr_kernel<<<B * KP1, 64, 0, stream>>>(idx1, cnt, nbr, pos1, v1, V1, knbr, kcnt, Z1);

    // ---- stage 2 (factorized a1) ----
    gemm_kernel<NH><<<512, 256, 0, stream>>>(hk, W2, t2);
    wsum_kernel<<<B * 8, 256, 0, stream>>>(t2, v1, wp);
    gcn2_kernel<<<B * 128, 256, 0, stream>>>(t2, wp, v1, Z1, knbr, kcnt, b2, h2);
    wsum_kernel<<<B * 8, 256, 0, stream>>>(h2, v1, wp);
    info2_kernel<<<B * 128, 256, 0, stream>>>(h2, wp, v1, Z1, knbr, kcnt, sc);
    topk_kernel<KP1, KP2, 512, false><<<B, 512, 0, stream>>>(sc, idx2, nullptr);
    gather_att_kernel<<<B * 64, 256, 0, stream>>>(h2, idx2, att2, h2k, lv, rv, KP2, KP1);
    readout_kernel<KP2, false><<<256, 256, 0, stream>>>(h2k, rout);
    a2_kernel<<<B * KP2, 256, 0, stream>>>(idx2, rv, v1, Z1, knbr, kcnt, a2);

    // ---- stage 3 (fused dense GCN + readout) ----
    gemm_kernel<NH><<<256, 256, 0, stream>>>(h2k, W3, t3);
    gcn3_fused_kernel<<<B * 8, 256, 0, stream>>>(a2, t3, b3, rout);

    // ---- classifier ----
    final_kernel<<<B, 256, 0, stream>>>(rout, Wlin, blin, out);
}

// Round 8
// 286.897 us; speedup vs baseline: 2.6580x; 1.1909x over previous
//
#include <hip/hip_runtime.h>

#define B    32
#define N1   1024
#define FIN  128
#define NH   256
#define KP1  512
#define KP2  256
#define NCLS 10
#define MAXD 64
#define E1   1.7182818284590452f   // e^LAMB - 1, LAMB = 1.0

typedef float4 F4;
typedef __attribute__((ext_vector_type(8))) short bf16x8;
typedef __attribute__((ext_vector_type(4))) float f32x4;

__device__ __forceinline__ void fma4(F4& a, float s, F4 v) {
    a.x += s * v.x; a.y += s * v.y; a.z += s * v.z; a.w += s * v.w;
}
__device__ __forceinline__ void add4(F4& a, F4 v) {
    a.x += v.x; a.y += v.y; a.z += v.z; a.w += v.w;
}
__device__ __forceinline__ void max4(F4& a, F4 v) {
    a.x = fmaxf(a.x, v.x); a.y = fmaxf(a.y, v.y); a.z = fmaxf(a.z, v.z); a.w = fmaxf(a.w, v.w);
}
__device__ __forceinline__ unsigned short f2bf(float f) {
    unsigned int u = __float_as_uint(f);
    u += 0x7fffu + ((u >> 16) & 1u);
    return (unsigned short)(u >> 16);
}
__device__ __forceinline__ float bf2f(unsigned short h) {
    return __uint_as_float(((unsigned int)h) << 16);
}

// ---------------- W split into MFMA-fragment-order bf16 hi/lo ----------------
// layout: elem[((nt*NKS + ks)*64 + lane)*8 + e] = W[ks*32 + (lane>>4)*8 + e][nt*16 + (lane&15)]
__global__ __launch_bounds__(256)
void wsplit_kernel(const float* __restrict__ W1, const float* __restrict__ W2,
                   const float* __restrict__ W3,
                   unsigned short* __restrict__ whi1, unsigned short* __restrict__ wlo1,
                   unsigned short* __restrict__ whi2, unsigned short* __restrict__ wlo2,
                   unsigned short* __restrict__ whi3, unsigned short* __restrict__ wlo3) {
    int T = blockIdx.x * 256 + threadIdx.x;   // 640 blocks -> 163840 elems
    const float* W; unsigned short *hi, *lo; int idx, kd;
    if (T < 32768)      { W = W1; hi = whi1; lo = wlo1; idx = T;         kd = 128; }
    else if (T < 98304) { W = W2; hi = whi2; lo = wlo2; idx = T - 32768; kd = 256; }
    else                { W = W3; hi = whi3; lo = wlo3; idx = T - 98304; kd = 256; }
    int e = idx & 7, lane = (idx >> 3) & 63;
    int nks = kd >> 5;                        // 4 or 8 (pow2)
    int ks = (idx >> 9) & (nks - 1);
    int nt = idx >> ((nks == 4) ? 11 : 12);
    int k = ks * 32 + ((lane >> 4) << 3) + e;
    int j = nt * 16 + (lane & 15);
    float v = W[k * 256 + j];
    unsigned short h = f2bf(v);
    hi[idx] = h;
    lo[idx] = f2bf(v - bf2f(h));
}

// ---------------- MFMA GEMM: out[M,256] = A[M,KD] @ W[KD,256], bf16x3 split ----------------
// block: 32 rows x 256 cols; 4 waves, each 32x64 (2 m-tiles x 4 n-tiles)
template<int KD>
__global__ __launch_bounds__(256, 4)
void gemm_mfma_kernel(const float* __restrict__ A, const unsigned short* __restrict__ Whi,
                      const unsigned short* __restrict__ Wlo, float* __restrict__ out) {
    constexpr int NKS = KD / 32;
    __shared__ unsigned short ahi[32][KD + 8];   // +8 pad: 2-way banks (free)
    __shared__ unsigned short alo[32][KD + 8];
    int tid = threadIdx.x;
    int m0 = blockIdx.x * 32;
    const float4* A4 = (const float4*)(A + (size_t)m0 * KD);
    for (int i = tid; i < 32 * (KD / 4); i += 256) {
        int r = i / (KD / 4), c = i % (KD / 4);
        float4 v = A4[i];
        int k = c * 4;
        unsigned short h0 = f2bf(v.x), h1 = f2bf(v.y), h2 = f2bf(v.z), h3 = f2bf(v.w);
        *(uint2*)&ahi[r][k] = make_uint2((unsigned)h0 | ((unsigned)h1 << 16),
                                         (unsigned)h2 | ((unsigned)h3 << 16));
        unsigned short l0 = f2bf(v.x - bf2f(h0)), l1 = f2bf(v.y - bf2f(h1));
        unsigned short l2 = f2bf(v.z - bf2f(h2)), l3 = f2bf(v.w - bf2f(h3));
        *(uint2*)&alo[r][k] = make_uint2((unsigned)l0 | ((unsigned)l1 << 16),
                                         (unsigned)l2 | ((unsigned)l3 << 16));
    }
    __syncthreads();
    int lane = tid & 63, wv = tid >> 6;
    int ln15 = lane & 15, q = lane >> 4;
    f32x4 acc[2][4] = {};
    const bf16x8* WH = (const bf16x8*)Whi;
    const bf16x8* WL = (const bf16x8*)Wlo;
    for (int ks = 0; ks < NKS; ++ks) {
        int kb = ks * 32 + q * 8;
        bf16x8 a0h = *(const bf16x8*)&ahi[ln15][kb];
        bf16x8 a0l = *(const bf16x8*)&alo[ln15][kb];
        bf16x8 a1h = *(const bf16x8*)&ahi[ln15 + 16][kb];
        bf16x8 a1l = *(const bf16x8*)&alo[ln15 + 16][kb];
        #pragma unroll
        for (int t = 0; t < 4; ++t) {
            int nt = wv * 4 + t;
            size_t off = (size_t)(nt * NKS + ks) * 64 + lane;
            bf16x8 bh = WH[off];
            bf16x8 bl = WL[off];
            acc[0][t] = __builtin_amdgcn_mfma_f32_16x16x32_bf16(a0h, bh, acc[0][t], 0, 0, 0);
            acc[1][t] = __builtin_amdgcn_mfma_f32_16x16x32_bf16(a1h, bh, acc[1][t], 0, 0, 0);
            acc[0][t] = __builtin_amdgcn_mfma_f32_16x16x32_bf16(a0l, bh, acc[0][t], 0, 0, 0);
            acc[1][t] = __builtin_amdgcn_mfma_f32_16x16x32_bf16(a1l, bh, acc[1][t], 0, 0, 0);
            acc[0][t] = __builtin_amdgcn_mfma_f32_16x16x32_bf16(a0h, bl, acc[0][t], 0, 0, 0);
            acc[1][t] = __builtin_amdgcn_mfma_f32_16x16x32_bf16(a1h, bl, acc[1][t], 0, 0, 0);
        }
    }
    #pragma unroll
    for (int mi = 0; mi < 2; ++mi)
        #pragma unroll
        for (int t = 0; t < 4; ++t) {
            int col = wv * 64 + t * 16 + ln15;
            #pragma unroll
            for (int r = 0; r < 4; ++r)
                out[(size_t)(m0 + mi * 16 + q * 4 + r) * 256 + col] = acc[mi][t][r];
        }
}

// ---------------- CSR build: wave-scan prefix, deterministic (column-ordered) ----------------
__global__ __launch_bounds__(256)
void csr_kernel(const float* __restrict__ adj, int* __restrict__ cnt,
                int* __restrict__ nbr, float* __restrict__ dgi,
                float* __restrict__ dia) {
    int row = blockIdx.x;                    // b*N1 + i
    const float* arow = adj + (size_t)row * N1;
    int t = threadIdx.x, lane = t & 63, wave = t >> 6;
    float4 v4 = ((const float4*)arow)[t];
    int loc[4];
    int c = 0;
    if (v4.x > 0.5f) loc[c++] = t * 4 + 0;
    if (v4.y > 0.5f) loc[c++] = t * 4 + 1;
    if (v4.z > 0.5f) loc[c++] = t * 4 + 2;
    if (v4.w > 0.5f) loc[c++] = t * 4 + 3;
    int x = c;
    #pragma unroll
    for (int s = 1; s < 64; s <<= 1) {
        int y = __shfl_up(x, s);
        if (lane >= s) x += y;
    }
    __shared__ int wtot[4];
    if (lane == 63) wtot[wave] = x;
    __syncthreads();
    int base = 0;
    #pragma unroll
    for (int w = 0; w < 4; ++w) base += (w < wave) ? wtot[w] : 0;
    int total = wtot[0] + wtot[1] + wtot[2] + wtot[3];
    int off = base + x - c;                  // exclusive prefix in column order
    for (int u = 0; u < c; ++u) {
        int p = off + u;
        if (p < MAXD) nbr[(size_t)row * MAXD + p] = loc[u];
    }
    if (t == 0) {
        cnt[row] = min(total, MAXD);
        dgi[row] = rsqrtf((float)total + 1.0f);            // deg of A=adj+I
        dia[row] = total > 0 ? 1.0f / (float)total : 0.0f; // deg of adj
    }
}

// ---------------- stage-1 GCN aggregate: wave-per-row, float4, shfl-broadcast ----------------
__global__ __launch_bounds__(256)
void gcn1_kernel(const float* __restrict__ t1, const int* __restrict__ cnt,
                 const int* __restrict__ nbr, const float* __restrict__ dgi,
                 const float* __restrict__ b1, float* __restrict__ h1) {
    int blk = blockIdx.x;                    // 32 b x 256 groups
    int b = blk & 31, g = blk >> 5;
    int lane = threadIdx.x & 63, wave = threadIdx.x >> 6;
    int i = g * 4 + wave;
    int row = (b << 10) + i;
    const F4* tb = (const F4*)(t1 + (((size_t)b << 10)) * NH);
    int n = cnt[row];
    int jv = 0; float dv = 0.f;
    if (lane < n) {
        jv = nbr[(size_t)row * MAXD + lane];
        dv = dgi[(b << 10) + jv];
    }
    F4 a0 = make_float4(0,0,0,0), a1 = a0, a2 = a0, a3 = a0;
    int e = 0;
    for (; e + 4 <= n; e += 4) {
        int j0 = __shfl(jv, e), j1 = __shfl(jv, e+1), j2 = __shfl(jv, e+2), j3 = __shfl(jv, e+3);
        float d0 = __shfl(dv, e), d1 = __shfl(dv, e+1), d2 = __shfl(dv, e+2), d3 = __shfl(dv, e+3);
        F4 v0 = tb[(size_t)j0 * 64 + lane]; F4 v1 = tb[(size_t)j1 * 64 + lane];
        F4 v2 = tb[(size_t)j2 * 64 + lane]; F4 v3 = tb[(size_t)j3 * 64 + lane];
        fma4(a0, d0, v0); fma4(a1, d1, v1); fma4(a2, d2, v2); fma4(a3, d3, v3);
    }
    for (; e < n; ++e) {
        int j = __shfl(jv, e); float d = __shfl(dv, e);
        fma4(a0, d, tb[(size_t)j * 64 + lane]);
    }
    add4(a0, a1); add4(a2, a3); add4(a0, a2);
    float di = dgi[row];
    F4 self = tb[(size_t)i * 64 + lane];
    F4 bb = ((const F4*)b1)[lane];
    F4 r;
    r.x = fmaxf(di * (a0.x + di * self.x) + bb.x, 0.f);
    r.y = fmaxf(di * (a0.y + di * self.y) + bb.y, 0.f);
    r.z = fmaxf(di * (a0.z + di * self.z) + bb.z, 0.f);
    r.w = fmaxf(di * (a0.w + di * self.w) + bb.w, 0.f);
    ((F4*)(h1 + (size_t)row * NH))[lane] = r;
}

// ---------------- stage-1 info score: wave-per-row, float4 ----------------
__global__ __launch_bounds__(256)
void info1_kernel(const float* __restrict__ h1, const int* __restrict__ cnt,
                  const int* __restrict__ nbr, const float* __restrict__ dia,
                  float* __restrict__ sc) {
    int blk = blockIdx.x;
    int b = blk & 31, g = blk >> 5;
    int lane = threadIdx.x & 63, wave = threadIdx.x >> 6;
    int i = g * 4 + wave;
    int row = (b << 10) + i;
    const F4* hb = (const F4*)(h1 + (((size_t)b << 10)) * NH);
    int n = cnt[row];
    int jv = 0;
    if (lane < n) jv = nbr[(size_t)row * MAXD + lane];
    F4 a0 = make_float4(0,0,0,0), a1 = a0, a2 = a0, a3 = a0;
    int e = 0;
    for (; e + 4 <= n; e += 4) {
        int j0 = __shfl(jv, e), j1 = __shfl(jv, e+1), j2 = __shfl(jv, e+2), j3 = __shfl(jv, e+3);
        add4(a0, hb[(size_t)j0 * 64 + lane]); add4(a1, hb[(size_t)j1 * 64 + lane]);
        add4(a2, hb[(size_t)j2 * 64 + lane]); add4(a3, hb[(size_t)j3 * 64 + lane]);
    }
    for (; e < n; ++e) {
        int j = __shfl(jv, e);
        add4(a0, hb[(size_t)j * 64 + lane]);
    }
    add4(a0, a1); add4(a2, a3); add4(a0, a2);
    float dd = dia[row];
    F4 self = hb[(size_t)i * 64 + lane];
    float val = fabsf(self.x - dd * a0.x) + fabsf(self.y - dd * a0.y)
              + fabsf(self.z - dd * a0.z) + fabsf(self.w - dd * a0.w);
    val += __shfl_xor(val, 32); val += __shfl_xor(val, 16);
    val += __shfl_xor(val, 8);  val += __shfl_xor(val, 4);
    val += __shfl_xor(val, 2);  val += __shfl_xor(val, 1);
    if (lane == 0) sc[row] = val;
}

// ---------------- top-k via bitonic sort (desc, tie: lower index first) ----------------
template<int NS, int KS, int NT, bool POS>
__global__ __launch_bounds__(512)
void topk_kernel(const float* __restrict__ sc, int* __restrict__ idxo,
                 int* __restrict__ pos) {
    int b = blockIdx.x;
    __shared__ float s[NS];
    __shared__ int id[NS];
    for (int i = threadIdx.x; i < NS; i += NT) { s[i] = sc[b * NS + i]; id[i] = i; }
    __syncthreads();
    for (int ksz = 2; ksz <= NS; ksz <<= 1) {
        for (int j = ksz >> 1; j > 0; j >>= 1) {
            for (int i = threadIdx.x; i < NS; i += NT) {
                int l = i ^ j;
                if (l > i) {
                    float si = s[i], sl = s[l];
                    int ii = id[i], il = id[l];
                    bool iBeforeL = (si > sl) || (si == sl && ii < il);
                    bool dirDesc = ((i & ksz) == 0);
                    if (dirDesc ? !iBeforeL : iBeforeL) {
                        s[i] = sl; s[l] = si; id[i] = il; id[l] = ii;
                    }
                }
            }
            __syncthreads();
        }
    }
    for (int t = threadIdx.x; t < KS; t += NT) idxo[b * KS + t] = id[t];
    if (POS)
        for (int t = threadIdx.x; t < NS; t += NT)
            pos[b * NS + id[t]] = (t < KS) ? t : -1;
}

// ---------------- gather pooled rows + attention dots: wave-per-row ----------------
__global__ __launch_bounds__(256)
void gather_att_kernel(const float* __restrict__ h, const int* __restrict__ idx,
                       const float* __restrict__ att, float* __restrict__ hk,
                       float* __restrict__ lv, float* __restrict__ rv,
                       int K, int Nsrc) {
    int blk = blockIdx.x;                    // 32 b x (K/4) groups
    int b = blk & 31, g = blk >> 5;
    int lane = threadIdx.x & 63, wave = threadIdx.x >> 6;
    int p = g * 4 + wave;
    int gg = b * K + p;
    int src = idx[gg];
    F4 v = ((const F4*)(h + ((size_t)b * Nsrc + src) * NH))[lane];
    ((F4*)(hk + (size_t)gg * NH))[lane] = v;
    F4 al = ((const F4*)att)[lane];
    F4 ar = ((const F4*)att)[64 + lane];
    float r1 = v.x * al.x + v.y * al.y + v.z * al.z + v.w * al.w;
    float r2 = v.x * ar.x + v.y * ar.y + v.z * ar.z + v.w * ar.w;
    r1 += __shfl_xor(r1, 32); r2 += __shfl_xor(r2, 32);
    r1 += __shfl_xor(r1, 16); r2 += __shfl_xor(r2, 16);
    r1 += __shfl_xor(r1, 8);  r2 += __shfl_xor(r2, 8);
    r1 += __shfl_xor(r1, 4);  r2 += __shfl_xor(r2, 4);
    r1 += __shfl_xor(r1, 2);  r2 += __shfl_xor(r2, 2);
    r1 += __shfl_xor(r1, 1);  r2 += __shfl_xor(r2, 1);
    if (lane == 0) { lv[gg] = r1; rv[gg] = r2; }
}

// ---------------- v = exp(r - rowmax), V = sum v (per batch) ----------------
__global__ __launch_bounds__(512)
void vexp_kernel(const float* __restrict__ rv, float* __restrict__ v1,
                 float* __restrict__ V1) {
    int b = blockIdx.x;
    int t = threadIdx.x;             // 512
    __shared__ float red[512];
    float r = rv[b * KP1 + t];
    red[t] = r;
    __syncthreads();
    for (int s = 256; s > 0; s >>= 1) {
        if (t < s) red[t] = fmaxf(red[t], red[t + s]);
        __syncthreads();
    }
    float mx = red[0];
    __syncthreads();
    float v = expf(r - mx);
    v1[b * KP1 + t] = v;
    red[t] = v;
    __syncthreads();
    for (int s = 256; s > 0; s >>= 1) {
        if (t < s) red[t] += red[t + s];
        __syncthreads();
    }
    if (t == 0) V1[b] = red[0];
}

// ---------------- induced-subgraph CSR on idx1 + Z1 (4 waves/block) ----------------
__global__ __launch_bounds__(256)
void knbr_kernel(const int* __restrict__ idx1, const int* __restrict__ cnt,
                 const int* __restrict__ nbr, const int* __restrict__ pos1,
                 const float* __restrict__ v1, const float* __restrict__ V1,
                 int* __restrict__ knbr, int* __restrict__ kcnt,
                 float* __restrict__ Z1) {
    int j = blockIdx.x;                      // 32 b x 128 groups
    int b = j & 31, pg = j >> 5;
    int lane = threadIdx.x & 63, wave = threadIdx.x >> 6;
    int p = pg * 4 + wave;
    int g = b * KP1 + p;
    int ip = idx1[g];
    int n = cnt[b * N1 + ip];
    int q = -1;
    if (lane < n) {
        int jj = nbr[(size_t)(b * N1 + ip) * MAXD + lane];
        q = pos1[b * N1 + jj];
    }
    bool kept = q >= 0;
    unsigned long long mask = __ballot(kept);
    int off = __popcll(mask & ((1ull << lane) - 1ull));
    if (kept) knbr[(size_t)g * MAXD + off] = q;
    float s = kept ? v1[b * KP1 + q] : 0.f;
    for (int o = 32; o > 0; o >>= 1) s += __shfl_down(s, o);
    if (lane == 0) { kcnt[g] = __popcll(mask); Z1[g] = V1[b] + E1 * s; }
}

// ---------------- per-batch weighted column sum (partials over 8 chunks) ----------------
__global__ __launch_bounds__(256)
void wsum_kernel(const float* __restrict__ X, const float* __restrict__ v1,
                 float* __restrict__ wp) {
    int blk = blockIdx.x;            // b*8 + c
    int b = blk >> 3, c = blk & 7;
    int f = threadIdx.x;
    float a0 = 0.f, a1 = 0.f, a2 = 0.f, a3 = 0.f;
    for (int q = c * 64; q < c * 64 + 64; q += 4) {
        a0 += v1[b * KP1 + q + 0] * X[(size_t)(b * KP1 + q + 0) * NH + f];
        a1 += v1[b * KP1 + q + 1] * X[(size_t)(b * KP1 + q + 1) * NH + f];
        a2 += v1[b * KP1 + q + 2] * X[(size_t)(b * KP1 + q + 2) * NH + f];
        a3 += v1[b * KP1 + q + 3] * X[(size_t)(b * KP1 + q + 3) * NH + f];
    }
    wp[(size_t)blk * NH + f] = (a0 + a1) + (a2 + a3);
}

// ---------------- stage-2 GCN via factorized a1: wave-per-row ----------------
__global__ __launch_bounds__(256)
void gcn2_kernel(const float* __restrict__ t2, const float* __restrict__ wp,
                 const float* __restrict__ v1, const float* __restrict__ Z1,
                 const int* __restrict__ knbr, const int* __restrict__ kcnt,
                 const float* __restrict__ b2, float* __restrict__ h2) {
    int blk = blockIdx.x;                    // 32 b x 128 groups
    int b = blk & 31, g = blk >> 5;
    int lane = threadIdx.x & 63, wave = threadIdx.x >> 6;
    int p = g * 4 + wave;
    int gg = (b << 9) + p;
    const F4* tb = (const F4*)(t2 + (((size_t)b << 9)) * NH);
    int n = kcnt[gg];
    int jv = 0; float wv = 0.f;
    if (lane < n) {
        jv = knbr[(size_t)gg * MAXD + lane];
        wv = v1[(b << 9) + jv];
    }
    F4 a0 = make_float4(0,0,0,0), a1 = a0, a2 = a0, a3 = a0;
    int e = 0;
    for (; e + 4 <= n; e += 4) {
        int j0 = __shfl(jv, e), j1 = __shfl(jv, e+1), j2 = __shfl(jv, e+2), j3 = __shfl(jv, e+3);
        float d0 = __shfl(wv, e), d1 = __shfl(wv, e+1), d2 = __shfl(wv, e+2), d3 = __shfl(wv, e+3);
        fma4(a0, d0, tb[(size_t)j0 * 64 + lane]); fma4(a1, d1, tb[(size_t)j1 * 64 + lane]);
        fma4(a2, d2, tb[(size_t)j2 * 64 + lane]); fma4(a3, d3, tb[(size_t)j3 * 64 + lane]);
    }
    for (; e < n; ++e) {
        int j = __shfl(jv, e); float d = __shfl(wv, e);
        fma4(a0, d, tb[(size_t)j * 64 + lane]);
    }
    add4(a0, a1); add4(a2, a3); add4(a0, a2);
    F4 w = make_float4(0,0,0,0);
    #pragma unroll
    for (int c = 0; c < 8; ++c) add4(w, ((const F4*)wp)[(size_t)(b * 8 + c) * 64 + lane]);
    float zi = 1.0f / Z1[gg];
    F4 tv = tb[(size_t)p * 64 + lane];
    F4 bb = ((const F4*)b2)[lane];
    F4 r;
    r.x = fmaxf(0.5f * ((w.x + E1 * a0.x) * zi + tv.x) + bb.x, 0.f);
    r.y = fmaxf(0.5f * ((w.y + E1 * a0.y) * zi + tv.y) + bb.y, 0.f);
    r.z = fmaxf(0.5f * ((w.z + E1 * a0.z) * zi + tv.z) + bb.z, 0.f);
    r.w = fmaxf(0.5f * ((w.w + E1 * a0.w) * zi + tv.w) + bb.w, 0.f);
    ((F4*)(h2 + (size_t)gg * NH))[lane] = r;
}

// ---------------- stage-2 info score via factorized a1: wave-per-row ----------------
__global__ __launch_bounds__(256)
void info2_kernel(const float* __restrict__ h2, const float* __restrict__ wp,
                  const float* __restrict__ v1, const float* __restrict__ Z1,
                  const int* __restrict__ knbr, const int* __restrict__ kcnt,
                  float* __restrict__ sc) {
    int blk = blockIdx.x;
    int b = blk & 31, g = blk >> 5;
    int lane = threadIdx.x & 63, wave = threadIdx.x >> 6;
    int p = g * 4 + wave;
    int gg = (b << 9) + p;
    const F4* hb = (const F4*)(h2 + (((size_t)b << 9)) * NH);
    int n = kcnt[gg];
    int jv = 0; float wv = 0.f;
    if (lane < n) {
        jv = knbr[(size_t)gg * MAXD + lane];
        wv = v1[(b << 9) + jv];
    }
    F4 a0 = make_float4(0,0,0,0), a1 = a0, a2 = a0, a3 = a0;
    int e = 0;
    for (; e + 4 <= n; e += 4) {
        int j0 = __shfl(jv, e), j1 = __shfl(jv, e+1), j2 = __shfl(jv, e+2), j3 = __shfl(jv, e+3);
        float d0 = __shfl(wv, e), d1 = __shfl(wv, e+1), d2 = __shfl(wv, e+2), d3 = __shfl(wv, e+3);
        fma4(a0, d0, hb[(size_t)j0 * 64 + lane]); fma4(a1, d1, hb[(size_t)j1 * 64 + lane]);
        fma4(a2, d2, hb[(size_t)j2 * 64 + lane]); fma4(a3, d3, hb[(size_t)j3 * 64 + lane]);
    }
    for (; e < n; ++e) {
        int j = __shfl(jv, e); float d = __shfl(wv, e);
        fma4(a0, d, hb[(size_t)j * 64 + lane]);
    }
    add4(a0, a1); add4(a2, a3); add4(a0, a2);
    F4 w = make_float4(0,0,0,0);
    #pragma unroll
    for (int c = 0; c < 8; ++c) add4(w, ((const F4*)wp)[(size_t)(b * 8 + c) * 64 + lane]);
    float zi = 1.0f / Z1[gg];
    F4 self = hb[(size_t)p * 64 + lane];
    float val = fabsf(self.x - (w.x + E1 * a0.x) * zi) + fabsf(self.y - (w.y + E1 * a0.y) * zi)
              + fabsf(self.z - (w.z + E1 * a0.z) * zi) + fabsf(self.w - (w.w + E1 * a0.w) * zi);
    val += __shfl_xor(val, 32); val += __shfl_xor(val, 16);
    val += __shfl_xor(val, 8);  val += __shfl_xor(val, 4);
    val += __shfl_xor(val, 2);  val += __shfl_xor(val, 1);
    if (lane == 0) sc[gg] = val;
}

// ---------------- materialize a2 = softmax(r2_q + a1k[p,q]) (XCD-clustered) ----------------
__global__ __launch_bounds__(256)
void a2_kernel(const int* __restrict__ idx2, const float* __restrict__ rv,
               const float* __restrict__ v1, const float* __restrict__ Z1,
               const int* __restrict__ knbr, const int* __restrict__ kcnt,
               float* __restrict__ a2) {
    int j = blockIdx.x;
    int b = j & 31, p = j >> 5;
    int g = b * KP2 + p;
    int q = threadIdx.x;             // 256
    int p2 = idx2[g];                // position in [0,KP1)
    int gp = b * KP1 + p2;
    __shared__ unsigned char flag[KP1];
    flag[q] = 0; flag[q + 256] = 0;
    __syncthreads();
    int n = kcnt[gp];
    if (q < n) flag[knbr[(size_t)gp * MAXD + q]] = 1;
    __syncthreads();
    int q2 = idx2[b * KP2 + q];
    float a1k = v1[b * KP1 + q2] * (flag[q2] ? (1.f + E1) : 1.f) / Z1[gp];
    float z = rv[b * KP2 + q] + a1k;       // l_p cancels in softmax
    __shared__ float red[256];
    red[q] = z;
    __syncthreads();
    for (int s = 128; s > 0; s >>= 1) {
        if (q < s) red[q] = fmaxf(red[q], red[q + s]);
        __syncthreads();
    }
    float mx = red[0];
    __syncthreads();
    float e = expf(z - mx);
    red[q] = e;
    __syncthreads();
    for (int s = 128; s > 0; s >>= 1) {
        if (q < s) red[q] += red[q + s];
        __syncthreads();
    }
    a2[(size_t)g * KP2 + q] = e / red[0];
}

// ---------------- readout: 256 blocks (b x 8 col-chunks) ----------------
template<int NROWS, bool INIT>
__global__ __launch_bounds__(256)
void readout_kernel(const float* __restrict__ h, float* __restrict__ rout) {
    int blk = blockIdx.x;
    int b = blk & 31, ch = blk >> 5;         // 8 chunks x 8 f4-cols
    int c = threadIdx.x & 7, rg = threadIdx.x >> 3;   // 8 f4-cols x 32 row-groups
    int f4 = ch * 8 + c;
    const F4* hb = (const F4*)(h + (size_t)b * NROWS * NH);
    F4 mx = make_float4(-1e30f, -1e30f, -1e30f, -1e30f);
    F4 sm = make_float4(0, 0, 0, 0);
    for (int r = rg; r < NROWS; r += 32) {
        F4 v = hb[(size_t)r * 64 + f4];
        max4(mx, v); add4(sm, v);
    }
    __shared__ F4 rmx[32][9], rsm[32][9];
    rmx[rg][c] = mx; rsm[rg][c] = sm;
    __syncthreads();
    for (int s = 16; s > 0; s >>= 1) {
        if (rg < s) {
            F4 m2 = rmx[rg + s][c], s2 = rsm[rg + s][c];
            max4(rmx[rg][c], m2); add4(rsm[rg][c], s2);
        }
        __syncthreads();
    }
    if (rg == 0) {
        F4 m = rmx[0][c], s4 = rsm[0][c];
        F4 rm, ra;
        rm.x = fmaxf(m.x, 0.f); rm.y = fmaxf(m.y, 0.f); rm.z = fmaxf(m.z, 0.f); rm.w = fmaxf(m.w, 0.f);
        const float inv = 1.0f / NROWS;
        ra.x = fmaxf(s4.x * inv, 0.f); ra.y = fmaxf(s4.y * inv, 0.f);
        ra.z = fmaxf(s4.z * inv, 0.f); ra.w = fmaxf(s4.w * inv, 0.f);
        F4* ro = (F4*)(rout + b * 512);
        if (INIT) {
            ro[f4] = rm; ro[64 + f4] = ra;
        } else {
            F4 o1 = ro[f4], o2 = ro[64 + f4];
            add4(o1, rm); add4(o2, ra);
            ro[f4] = o1; ro[64 + f4] = o2;
        }
    }
}

// ---------------- fused stage-3: h3 = relu(0.5*(a2@t3 + t3) + b3) -> readout += ----------------
__global__ __launch_bounds__(256, 2)
void gcn3_fused_kernel(const float* __restrict__ a2, const float* __restrict__ t3,
                       const float* __restrict__ b3, float* __restrict__ rout) {
    constexpr int KC = 16;
    __shared__ float sa[KC][260];            // padded: conflict-free staging
    __shared__ float st[KC][32];
    int b = blockIdx.x >> 3;
    int cb = (blockIdx.x & 7) * 32;
    int tid = threadIdx.x;
    int ct = tid & 7, rt = tid >> 3;
    int c0 = cb + ct * 4, r0 = rt * 8;
    const float* ab = a2 + (size_t)b * KP2 * KP2;
    const float* tb = t3 + (size_t)b * KP2 * NH;
    float acc[8][4] = {};
    for (int q0 = 0; q0 < KP2; q0 += KC) {
        const float4* A4 = (const float4*)ab;
        for (int i = tid; i < 256 * (KC / 4); i += 256) {
            int r = i >> 2, j = i & 3;
            float4 v = A4[(size_t)r * 64 + q0 / 4 + j];
            sa[j * 4 + 0][r] = v.x; sa[j * 4 + 1][r] = v.y;
            sa[j * 4 + 2][r] = v.z; sa[j * 4 + 3][r] = v.w;
        }
        if (tid < KC * 8) {
            int q = tid >> 3, c4 = tid & 7;
            *(float4*)&st[q][c4 * 4] = *(const float4*)&tb[(size_t)(q0 + q) * NH + cb + c4 * 4];
        }
        __syncthreads();
        #pragma unroll
        for (int q = 0; q < KC; ++q) {
            float tv[4], av[8];
            *(float4*)&tv[0] = *(const float4*)&st[q][ct * 4];
            *(float4*)&av[0] = *(const float4*)&sa[q][r0];
            *(float4*)&av[4] = *(const float4*)&sa[q][r0 + 4];
            #pragma unroll
            for (int r = 0; r < 8; ++r)
                #pragma unroll
                for (int c = 0; c < 4; ++c)
                    acc[r][c] += av[r] * tv[c];
        }
        __syncthreads();
    }
    float bv[4];
    *(float4*)&bv[0] = *(const float4*)&b3[c0];
    float mx[4] = {-1e30f, -1e30f, -1e30f, -1e30f}, sm[4] = {};
    for (int r = 0; r < 8; ++r) {
        float4 t4 = *(const float4*)&tb[(size_t)(r0 + r) * NH + c0];
        float tvv[4] = {t4.x, t4.y, t4.z, t4.w};
        #pragma unroll
        for (int c = 0; c < 4; ++c) {
            float h = fmaxf(0.5f * (acc[r][c] + tvv[c]) + bv[c], 0.f);
            mx[c] = fmaxf(mx[c], h);
            sm[c] += h;
        }
    }
    __shared__ float rmx2[32][33], rsm2[32][33];
    #pragma unroll
    for (int c = 0; c < 4; ++c) { rmx2[ct * 4 + c][rt] = mx[c]; rsm2[ct * 4 + c][rt] = sm[c]; }
    __syncthreads();
    if (tid < 32) {
        float m = -1e30f, s = 0.f;
        for (int r = 0; r < 32; ++r) { m = fmaxf(m, rmx2[tid][r]); s += rsm2[tid][r]; }
        rout[b * 512 + cb + tid] += fmaxf(m, 0.f);
        rout[b * 512 + NH + cb + tid] += fmaxf(s * (1.f / KP2), 0.f);
    }
}

// ---------------- final linear (parallel over f-chunks) ----------------
__global__ __launch_bounds__(256)
void final_kernel(const float* __restrict__ rout, const float* __restrict__ Wlin,
                  const float* __restrict__ blin, float* __restrict__ out) {
    int b = blockIdx.x;
    int tid = threadIdx.x;
    int c = tid & 15, fg = tid >> 4;         // 16 f-groups x 16 (10 used) cols
    float acc = 0.f;
    if (c < NCLS) {
        for (int k = 0; k < 32; ++k) {
            int f = fg * 32 + k;
            acc += rout[b * 512 + f] * Wlin[f * NCLS + c];
        }
    }
    __shared__ float red[16][16];
    red[fg][c] = acc;
    __syncthreads();
    if (tid < 16 && c < NCLS) {
        float a = blin[c];
        #pragma unroll
        for (int k = 0; k < 16; ++k) a += red[k][c];
        out[b * NCLS + c] = a;
    }
}

extern "C" void kernel_launch(void* const* d_in, const int* in_sizes, int n_in,
                              void* d_out, int out_size, void* d_ws, size_t ws_size,
                              hipStream_t stream) {
    const float* x    = (const float*)d_in[0];
    const float* adj  = (const float*)d_in[1];
    const float* W1   = (const float*)d_in[2];
    const float* b1   = (const float*)d_in[3];
    const float* W2   = (const float*)d_in[4];
    const float* b2   = (const float*)d_in[5];
    const float* W3   = (const float*)d_in[6];
    const float* b3   = (const float*)d_in[7];
    const float* att1 = (const float*)d_in[8];
    const float* att2 = (const float*)d_in[9];
    const float* Wlin = (const float*)d_in[10];
    const float* blin = (const float*)d_in[11];
    float* out = (float*)d_out;

    float* fws = (float*)d_ws;
    float* t1  = fws;                        // 8,388,608 floats
    float* h1  = t1 + 8388608;               // 8,388,608
    float* hk  = h1 + 8388608;               // 4,194,304
    float* dgi = hk + 4194304;               // 32768
    float* dia = dgi + 32768;                // 32768
    float* sc  = dia + 32768;                // 32768
    float* lv  = sc + 32768;                 // 16384
    float* rv  = lv + 16384;                 // 16384
    float* rout = rv + 16384;                // 16384
    float* v1  = rout + 16384;               // 16384
    float* V1  = v1 + 16384;                 // 64 (padded)
    float* Z1  = V1 + 64;                    // 16384
    float* wp  = Z1 + 16384;                 // 32*8*256 = 65536
    int* cnt  = (int*)(wp + 65536);          // 32768
    int* nbr  = cnt + 32768;                 // 32768*64 = 2,097,152
    int* idx1 = nbr + 32768 * MAXD;          // 16384
    int* idx2 = idx1 + 16384;                // 8192
    int* pos1 = idx2 + 8192;                 // 32768
    unsigned short* whi1 = (unsigned short*)(pos1 + 32768);   // 32768 ushorts
    unsigned short* wlo1 = whi1 + 32768;
    unsigned short* whi2 = wlo1 + 32768;     // 65536
    unsigned short* wlo2 = whi2 + 65536;
    unsigned short* whi3 = wlo2 + 65536;
    unsigned short* wlo3 = whi3 + 65536;
    // aliases (lifetime-disjoint reuse)
    float* t2   = h1;                        // stage-2 XW   [B*KP1*NH]
    float* h2   = h1 + 4194304;              // stage-2 hidden
    float* h2k  = hk;                        // stage-2 pooled rows
    float* a2   = t1;                        // [B*KP2*KP2] = 2,097,152 (t1 dead after gcn1)
    float* t3   = t1 + 2097152;              // 2,097,152
    int*   knbr = (int*)(t1 + 6291456);      // 16384*64 = 1,048,576 ints
    int*   kcnt = knbr + 16384 * MAXD;       // 16384

    // ---- W pre-split (fragment-order bf16 hi/lo) ----
    wsplit_kernel<<<640, 256, 0, stream>>>(W1, W2, W3, whi1, wlo1, whi2, wlo2, whi3, wlo3);

    // ---- stage 1 (sparse binary graph) ----
    gemm_mfma_kernel<FIN><<<1024, 256, 0, stream>>>(x, whi1, wlo1, t1);
    csr_kernel<<<B * N1, 256, 0, stream>>>(adj, cnt, nbr, dgi, dia);
    gcn1_kernel<<<B * 256, 256, 0, stream>>>(t1, cnt, nbr, dgi, b1, h1);
    info1_kernel<<<B * 256, 256, 0, stream>>>(h1, cnt, nbr, dia, sc);
    topk_kernel<N1, KP1, 512, true><<<B, 512, 0, stream>>>(sc, idx1, pos1);
    gather_att_kernel<<<B * 128, 256, 0, stream>>>(h1, idx1, att1, hk, lv, rv, KP1, N1);
    readout_kernel<KP1, true><<<256, 256, 0, stream>>>(hk, rout);

    // ---- pool-1 factorization: a1[p,q] = v_q*(1+E1*adjk)/Z_p ----
    vexp_kernel<<<B, 512, 0, stream>>>(rv, v1, V1);
    knbr_kernel<<<B * 128, 256, 0, stream>>>(idx1, cnt, nbr, pos1, v1, V1, knbr, kcnt, Z1);

    // ---- stage 2 (factorized a1) ----
    gemm_mfma_kernel<NH><<<512, 256, 0, stream>>>(hk, whi2, wlo2, t2);
    wsum_kernel<<<B * 8, 256, 0, stream>>>(t2, v1, wp);
    gcn2_kernel<<<B * 128, 256, 0, stream>>>(t2, wp, v1, Z1, knbr, kcnt, b2, h2);
    wsum_kernel<<<B * 8, 256, 0, stream>>>(h2, v1, wp);
    info2_kernel<<<B * 128, 256, 0, stream>>>(h2, wp, v1, Z1, knbr, kcnt, sc);
    topk_kernel<KP1, KP2, 512, false><<<B, 512, 0, stream>>>(sc, idx2, nullptr);
    gather_att_kernel<<<B * 64, 256, 0, stream>>>(h2, idx2, att2, h2k, lv, rv, KP2, KP1);
    readout_kernel<KP2, false><<<256, 256, 0, stream>>>(h2k, rout);
    a2_kernel<<<B * KP2, 256, 0, stream>>>(idx2, rv, v1, Z1, knbr, kcnt, a2);

    // ---- stage 3 (fused dense GCN + readout) ----
    gemm_mfma_kernel<NH><<<256, 256, 0, stream>>>(h2k, whi3, wlo3, t3);
    gcn3_fused_kernel<<<B * 8, 256, 0, stream>>>(a2, t3, b3, rout);

    // ---- classifier ----
    final_kernel<<<B, 256, 0, stream>>>(rout, Wlin, blin, out);
}